// Round 9
// baseline (6867.413 us; speedup 1.0000x reference)
//
#include <hip/hip_runtime.h>

#define SLEN  128
#define BATCH 64
#define EMB   512
#define HID   512
#define DDEC  1024
#define ATT   256
#define VOC   32000
#define TSTEPS 63
#define SLOT  1024   // ints per 4KB slot

typedef _Float16 f16x4 __attribute__((ext_vector_type(4)));
typedef _Float16 f16x8 __attribute__((ext_vector_type(8)));
typedef float    f32x4 __attribute__((ext_vector_type(4)));

union HQ  { unsigned long long q[2]; f16x8 v; };
union HP  { _Float16 h[2]; unsigned u; };
union HP4 { _Float16 h[4]; f16x4 v4; unsigned long long u; };

__device__ __forceinline__ float sigmoidf_(float x) { return 1.0f / (1.0f + __expf(-x)); }
__device__ __forceinline__ float tanhf_(float x)    { return 1.0f - 2.0f / (__expf(2.0f * x) + 1.0f); }

__device__ __forceinline__ void st_u32(void* p, unsigned v) {
    __hip_atomic_store((unsigned*)p, v, __ATOMIC_RELAXED, __HIP_MEMORY_SCOPE_AGENT);
}
__device__ __forceinline__ void st_u64(void* p, unsigned long long v) {
    __hip_atomic_store((unsigned long long*)p, v, __ATOMIC_RELAXED, __HIP_MEMORY_SCOPE_AGENT);
}
__device__ __forceinline__ unsigned long long ld_u64(const void* p) {
    return __hip_atomic_load((const unsigned long long*)p, __ATOMIC_RELAXED, __HIP_MEMORY_SCOPE_AGENT);
}
__device__ __forceinline__ void st_i32(int* p, int v) {
    __hip_atomic_store(p, v, __ATOMIC_RELAXED, __HIP_MEMORY_SCOPE_AGENT);
}
__device__ __forceinline__ int ld_i32(const int* p) {
    return __hip_atomic_load(p, __ATOMIC_RELAXED, __HIP_MEMORY_SCOPE_AGENT);
}

// flag/epoch grid barrier: flags 4KB apart, detector block publishes gen.
__device__ __forceinline__ void barf(int* flags, int* gen, int narr, int myid,
                                     int epoch, bool amDet) {
    __syncthreads();
    if (amDet) {
        if (threadIdx.x == 0 && myid < narr) st_i32(flags + myid * SLOT, epoch);
        if ((int)threadIdx.x < narr) {
            while (ld_i32(flags + threadIdx.x * SLOT) < epoch)
                __builtin_amdgcn_s_sleep(2);
        }
        __syncthreads();
        if (threadIdx.x == 0) st_i32(gen, epoch);
    } else {
        if (threadIdx.x == 0) {
            if (myid < narr) st_i32(flags + myid * SLOT, epoch);
            while (ld_i32(gen) < epoch)
                __builtin_amdgcn_s_sleep(4);
        }
    }
    __syncthreads();
}

// ================= init =================
__global__ __launch_bounds__(256) void init_convert(
    const int* __restrict__ src, const int* __restrict__ trg,
    const float* __restrict__ enc_emb, const float* __restrict__ dec_emb,
    const float* __restrict__ Wf_ih, const float* __restrict__ Wf_hh,
    const float* __restrict__ Wb_ih, const float* __restrict__ Wb_hh,
    const float* __restrict__ Wa, const float* __restrict__ Wd_ih, const float* __restrict__ Wd_hh,
    float* __restrict__ out0,
    _Float16* __restrict__ Wenc16, _Float16* __restrict__ Wd16, _Float16* __restrict__ Wa16,
    _Float16* __restrict__ emb_src16, _Float16* __restrict__ predA,
    float* __restrict__ c_enc, _Float16* __restrict__ h16_enc, int* __restrict__ bar_ws)
{
    long idx = (long)blockIdx.x * 256 + threadIdx.x;
    if (idx < 2048000L) { out0[idx] = 0.f; return; }
    idx -= 2048000L;
    if (idx < 4194304L) {   // Wenc16 [dir][2048][1024]
        int dir = (int)(idx >> 21);
        int rem = (int)(idx & ((1 << 21) - 1));
        int rr = rem >> 10, c = rem & 1023;
        int d = rr >> 2, qg = rr & 3;
        const float* Wih = dir ? Wb_ih : Wf_ih;
        const float* Whh = dir ? Wb_hh : Wf_hh;
        float v = (c < 512) ? Wih[(long)(qg * 512 + d) * 512 + c]
                            : Whh[(long)(qg * 512 + d) * 512 + (c - 512)];
        Wenc16[idx] = (_Float16)v; return;
    }
    idx -= 4194304L;
    if (idx < 10485760L) {  // Wd16 [4096][2560]
        int rr = (int)(idx / 2560), c = (int)(idx % 2560);
        int d = rr >> 2, qg = rr & 3;
        float v = (c < 1536) ? Wd_ih[(long)(qg * 1024 + d) * 1536 + c]
                             : Wd_hh[(long)(qg * 1024 + d) * 1024 + (c - 1536)];
        Wd16[idx] = (_Float16)v; return;
    }
    idx -= 10485760L;
    if (idx < 262144L) {    // Wa16 [256][1024]
        int rr = (int)(idx >> 10), c = (int)(idx & 1023);
        Wa16[idx] = (_Float16)Wa[(long)rr * 2048 + c]; return;
    }
    idx -= 262144L;
    if (idx < 4194304L) {   // emb_src16
        int sb = (int)(idx >> 9), e = (int)(idx & 511);
        int tok = src[sb];
        emb_src16[idx] = (_Float16)enc_emb[(long)tok * 512 + e]; return;
    }
    idx -= 4194304L;
    if (idx < 2064384L) {   // predA emb cols
        int rI = (int)(idx >> 9), e = (int)(idx & 511);
        int tok = trg[rI];
        predA[(long)(64 + rI) * 2560 + 2048 + e] = (_Float16)dec_emb[(long)tok * 512 + e]; return;
    }
    idx -= 2064384L;
    if (idx < 65536L) { c_enc[idx] = 0.f; return; }
    idx -= 65536L;
    if (idx < 65536L) { h16_enc[idx] = (_Float16)0.f; return; }
    idx -= 65536L;
    if (idx < 332800L) { bar_ws[idx] = 0; }   // 325 slots x 1024 ints
}

// ================= cooperative encoder: 4 groups (dir x batch-half) x 64 blocks x 256 thr =================
__global__ __launch_bounds__(256, 1) void enc_coop(
    const _Float16* __restrict__ Wenc16, const _Float16* __restrict__ emb_src16,
    _Float16* __restrict__ h16_enc, float* __restrict__ c_enc,
    const float* __restrict__ bf, const float* __restrict__ bb,
    _Float16* __restrict__ enc_out16, int* __restrict__ bar_ws)
{
    __shared__ _Float16 Wl[32768];       // 64KB [kc32][gt2][512]
    __shared__ _Float16 Xs[32 * 1024];   // 64KB, 32 rows x 2048B, XOR-swizzled
    __shared__ float gbuf[32][34];

    const int t = threadIdx.x, lane = t & 63, wv = t >> 6;
    const int blk = blockIdx.x;
    const int g = blk >> 6, wb = blk & 63;
    const int dir = g >> 1, bh = g & 1;
    const int r16 = lane & 15, kg = lane >> 4;
    int* gflags = bar_ws + (65 + g * 65) * SLOT;
    int* ggen   = gflags + 64 * SLOT;
    const bool amDet = (wb == 63);

    // stage weight slice: 32 gate rows (d in [wb*8, wb*8+8)), fragment-linear
    #pragma unroll
    for (int i = 0; i < 16; ++i) {
        int h0 = (i * 256 + t) * 8;
        int kc = h0 >> 10;
        int rem = h0 & 1023;
        int gt = rem >> 9, l = (rem >> 3) & 63;
        f16x8 v = *(const f16x8*)(Wenc16 +
            ((size_t)(dir * 2048 + wb * 32 + gt * 16 + (l & 15))) * 1024 + (l >> 4) * 8 + kc * 32);
        *(f16x8*)&Wl[h0] = v;
    }

    const float* bias = dir ? bb : bf;
    const int pb = t & 31, dp = t >> 5;       // pointwise: t<128 -> dp 0..3
    const int dl0 = dp * 2;
    float bias2[2][4], creg2[2] = {0.f, 0.f};
    if (t < 128) {
        #pragma unroll
        for (int j = 0; j < 2; ++j)
            #pragma unroll
            for (int q = 0; q < 4; ++q)
                bias2[j][q] = bias[q * 512 + wb * 8 + dl0 + j];
    }
    __syncthreads();

    for (int s = 0; s < SLEN; ++s) {
        const int par = s & 1;
        const int s_eff = dir ? (127 - s) : s;
        // stage activations: 32 batch rows x [emb(512) | h(512)]
        #pragma unroll
        for (int i = 0; i < 8; ++i) {
            int slot = i * 256 + t;
            int row = slot >> 6, c8 = slot & 63;
            f16x8 v = *(const f16x8*)(emb_src16 +
                ((size_t)(s_eff * 64 + bh * 32 + row)) * 512 + c8 * 8);
            *(f16x8*)((char*)Xs + row * 2048 + ((c8 * 16) ^ ((row & 7) << 4))) = v;
        }
        #pragma unroll
        for (int i = 0; i < 8; ++i) {
            int slot = i * 256 + t;
            int row = slot >> 6, c8 = slot & 63;
            const unsigned long long* hp = (const unsigned long long*)(h16_enc +
                ((size_t)((par * 2 + dir) * 64 + bh * 32 + row)) * 512 + c8 * 8);
            HQ hq; hq.q[0] = ld_u64(hp); hq.q[1] = ld_u64(hp + 1);
            *(f16x8*)((char*)Xs + row * 2048 + (((64 + c8) * 16) ^ ((row & 7) << 4))) = hq.v;
        }
        __syncthreads();
        // MFMA: wave wv: gate tile gt = wv&1, batch tile mb = wv>>1
        {
            const int gt = wv & 1, mb = wv >> 1;
            const int arow = mb * 16 + r16;
            f32x4 acc = {};
            #pragma unroll 8
            for (int kc = 0; kc < 32; ++kc) {
                f16x8 bw = *(const f16x8*)&Wl[kc * 1024 + gt * 512 + lane * 8];
                f16x8 a = *(const f16x8*)((char*)Xs + arow * 2048 +
                           ((kg * 16 + kc * 64) ^ ((arow & 7) << 4)));
                acc = __builtin_amdgcn_mfma_f32_16x16x32_f16(a, bw, acc, 0, 0, 0);
            }
            // C/D: col=lane&15 -> gate row, row=kg*4+rI -> batch   (FIXED)
            #pragma unroll
            for (int rI = 0; rI < 4; ++rI)
                gbuf[gt * 16 + (lane & 15)][mb * 16 + kg * 4 + rI] = acc[rI];
        }
        __syncthreads();
        if (t < 128) {
            HP hp;
            #pragma unroll
            for (int j = 0; j < 2; ++j) {
                const int dl = dl0 + j;
                float g0 = gbuf[dl * 4 + 0][pb] + bias2[j][0];
                float g1 = gbuf[dl * 4 + 1][pb] + bias2[j][1];
                float g2 = gbuf[dl * 4 + 2][pb] + bias2[j][2];
                float g3 = gbuf[dl * 4 + 3][pb] + bias2[j][3];
                float c2 = sigmoidf_(g1) * creg2[j] + sigmoidf_(g0) * tanhf_(g2);
                float h2 = sigmoidf_(g3) * tanhf_(c2);
                creg2[j] = c2;
                hp.h[j] = (_Float16)h2;
            }
            const int bglob = bh * 32 + pb;
            const int d0 = wb * 8 + dl0;
            st_u32((void*)(h16_enc + ((size_t)((par ^ 1) * 2 + dir) * 64 + bglob) * 512 + d0), hp.u);
            *(unsigned*)(enc_out16 + ((size_t)s_eff * 64 + bglob) * 1024 + dir * 512 + d0) = hp.u;
        }
        barf(gflags, ggen, 64, wb, s + 1, amDet);
    }
    if (t < 128) {
        const int bglob = bh * 32 + pb;
        const int d0 = wb * 8 + dl0;
        c_enc[((size_t)dir * 64 + bglob) * 512 + d0] = creg2[0];
        c_enc[((size_t)dir * 64 + bglob) * 512 + d0 + 1] = creg2[1];
    }
}

// ================= cooperative decoder: 64 blocks x 512 thr =================
// Block wb: attention for batch wb + gates for d in [wb*16, wb*16+16), all 64 batch.
__global__ __launch_bounds__(512, 1) void dec_coop(
    const _Float16* __restrict__ Wd16, const _Float16* __restrict__ Wa16,
    const float* __restrict__ bd, const float* __restrict__ vvec,
    const int* __restrict__ src, const _Float16* __restrict__ enc_part16,
    const _Float16* __restrict__ enc_out16, const float* __restrict__ c_enc,
    _Float16* __restrict__ predA, int* __restrict__ bar_ws)
{
    __shared__ _Float16 Xs[64 * 512];    // 64KB A-chunk [64 rows x 512 halves], XOR-swizzled
    __shared__ float gbuf[64][66];
    __shared__ float ha[256], sv[256], sc[128], red[128];

    const int t = threadIdx.x, lane = t & 63, wv = t >> 6;   // wv 0..7
    const int wb = blockIdx.x;
    const int r16 = lane & 15, kg = lane >> 4;
    int* gflags = bar_ws;
    int* ggen   = gflags + 64 * SLOT;
    const bool amDet = (wb == 63);

    // c regs + bias: all 512 threads: b = t&63, d pair dl0 = (t>>6)*2
    const int pb = t & 63;
    const int dl0 = (t >> 6) * 2;
    float bias2[2][4], creg2[2];
    #pragma unroll
    for (int j = 0; j < 2; ++j) {
        const int dg = wb * 16 + dl0 + j;
        #pragma unroll
        for (int q = 0; q < 4; ++q) bias2[j][q] = bd[q * 1024 + dg];
        creg2[j] = (dg < 512) ? c_enc[(size_t)pb * 512 + dg]
                              : c_enc[(size_t)(64 + pb) * 512 + (dg - 512)];
    }
    if (t < 256) sv[t] = vvec[t];

    // h0 for batch wb -> predA row wb
    {
        int d = t * 2;
        const size_t rbase = (d < 512) ? (size_t)(127 * 64 + wb) * 1024
                                       : (size_t)(0 * 64 + wb) * 1024;
        HP hp;
        hp.h[0] = enc_out16[rbase + d];
        hp.h[1] = enc_out16[rbase + d + 1];
        st_u32((void*)(predA + (size_t)wb * 2560 + d), hp.u);
    }
    barf(gflags, ggen, 64, wb, 1, amDet);

    for (int tt = 0; tt < TSTEPS; ++tt) {
        // ---- P1: hatt for batch wb (16-batch-group MFMA), waves 0..3
        if (t < 256) {
            const int base_m = wb & 48;
            const _Float16* Ahh = predA + ((size_t)(tt * 64 + base_m + r16)) * 2560 + kg * 8;
            f32x4 acc4[4] = {};
            #pragma unroll 4
            for (int kc = 0; kc < 32; ++kc) {
                f16x8 a = *(const f16x8*)(Ahh + kc * 32);
                #pragma unroll
                for (int jj = 0; jj < 4; ++jj) {
                    f16x8 bw = *(const f16x8*)(Wa16 +
                        ((size_t)((wv * 4 + jj) * 16 + r16)) * 1024 + kg * 8 + kc * 32);
                    acc4[jj] = __builtin_amdgcn_mfma_f32_16x16x32_f16(a, bw, acc4[jj], 0, 0, 0);
                }
            }
            if (kg == ((wb & 15) >> 2)) {
                #pragma unroll
                for (int jj = 0; jj < 4; ++jj)
                    ha[(wv * 4 + jj) * 16 + r16] = acc4[jj][wb & 3];
            }
        }
        __syncthreads();
        // ---- P2: energy + softmax + ctx for batch wb
        if (t < 128) {
            const f16x8* ep = (const f16x8*)(enc_part16 + ((size_t)t * 64 + wb) * 256);
            float acc = 0.f;
            #pragma unroll 4
            for (int j8 = 0; j8 < 32; ++j8) {
                f16x8 e = ep[j8];
                #pragma unroll
                for (int u = 0; u < 8; ++u)
                    acc += tanhf_(ha[j8 * 8 + u] + (float)e[u]) * sv[j8 * 8 + u];
            }
            float scv = (src[t * 64 + wb] != 0) ? acc : -1e10f;
            sc[t] = scv; red[t] = scv;
        }
        __syncthreads();
        for (int off = 64; off > 0; off >>= 1) { if (t < off) red[t] = fmaxf(red[t], red[t + off]); __syncthreads(); }
        const float mx = red[0];
        __syncthreads();
        if (t < 128) { float e = __expf(sc[t] - mx); sc[t] = e; red[t] = e; }
        __syncthreads();
        for (int off = 64; off > 0; off >>= 1) { if (t < off) red[t] += red[t + off]; __syncthreads(); }
        const float inv = 1.0f / red[0];
        __syncthreads();
        if (t < 256) {
            float a0 = 0.f, a1 = 0.f, a2 = 0.f, a3 = 0.f;
            for (int sI = 0; sI < 128; ++sI) {
                float as = sc[sI] * inv;
                f16x4 ev = *(const f16x4*)(enc_out16 + ((size_t)sI * 64 + wb) * 1024 + t * 4);
                a0 += as * (float)ev[0]; a1 += as * (float)ev[1];
                a2 += as * (float)ev[2]; a3 += as * (float)ev[3];
            }
            HP4 o;
            o.h[0] = (_Float16)a0; o.h[1] = (_Float16)a1;
            o.h[2] = (_Float16)a2; o.h[3] = (_Float16)a3;
            st_u64((void*)(predA + ((size_t)(64 + tt * 64 + wb)) * 2560 + 1024 + t * 4), o.u);
        }
        barf(gflags, ggen, 64, wb, 2 * tt + 2, amDet);

        // ---- P3: gates 64 rows x 64 batch; A staged in LDS per 512-half chunk, Wd from L2
        {
            const int gt = wv & 3;          // gate tile (16 rows)
            const int bh = wv >> 2;         // batch half
            f32x4 acc2[2] = {};
            #pragma unroll
            for (int c = 0; c < 5; ++c) {
                int rb, cb;
                if      (c == 0) { rb = 64 + tt * 64; cb = 2048; }   // emb   (W cols 0..511)
                else if (c == 1) { rb = 64 + tt * 64; cb = 1024; }   // ctx lo (W 512..1023)
                else if (c == 2) { rb = 64 + tt * 64; cb = 1536; }   // ctx hi (W 1024..1535)
                else if (c == 3) { rb = tt * 64;      cb = 0;    }   // h lo   (W 1536..2047)
                else             { rb = tt * 64;      cb = 512;  }   // h hi   (W 2048..2559)
                __syncthreads();
                #pragma unroll
                for (int i = 0; i < 8; ++i) {
                    int slot = i * 512 + t;
                    int row = slot >> 6, c8 = slot & 63;
                    f16x8 v = *(const f16x8*)(predA + (size_t)(rb + row) * 2560 + cb + c8 * 8);
                    *(f16x8*)((char*)Xs + row * 1024 + ((c8 * 16) ^ ((row & 7) << 4))) = v;
                }
                __syncthreads();
                const _Float16* Bp = Wd16 + (size_t)(wb * 64 + gt * 16 + r16) * 2560 + c * 512 + kg * 8;
                #pragma unroll 4
                for (int kcL = 0; kcL < 16; ++kcL) {
                    f16x8 bw = *(const f16x8*)(Bp + kcL * 32);
                    #pragma unroll
                    for (int m = 0; m < 2; ++m) {
                        const int arow = bh * 32 + m * 16 + r16;
                        f16x8 a = *(const f16x8*)((char*)Xs + arow * 1024 +
                                   ((kg * 16 + kcL * 64) ^ ((arow & 7) << 4)));
                        acc2[m] = __builtin_amdgcn_mfma_f32_16x16x32_f16(a, bw, acc2[m], 0, 0, 0);
                    }
                }
            }
            // C/D: col=lane&15 -> gate row, row=kg*4+rI -> batch   (FIXED)
            #pragma unroll
            for (int m = 0; m < 2; ++m)
                #pragma unroll
                for (int rI = 0; rI < 4; ++rI)
                    gbuf[gt * 16 + (lane & 15)][bh * 32 + m * 16 + kg * 4 + rI] = acc2[m][rI];
        }
        __syncthreads();
        // pointwise: all 512 threads, 2 d each
        {
            HP hp;
            #pragma unroll
            for (int j = 0; j < 2; ++j) {
                const int dl = dl0 + j;
                float g0 = gbuf[dl * 4 + 0][pb] + bias2[j][0];
                float g1 = gbuf[dl * 4 + 1][pb] + bias2[j][1];
                float g2 = gbuf[dl * 4 + 2][pb] + bias2[j][2];
                float g3 = gbuf[dl * 4 + 3][pb] + bias2[j][3];
                float c2 = sigmoidf_(g1) * creg2[j] + sigmoidf_(g0) * tanhf_(g2);
                float h2 = sigmoidf_(g3) * tanhf_(c2);
                creg2[j] = c2;
                hp.h[j] = (_Float16)h2;
            }
            st_u32((void*)(predA + ((size_t)(64 + tt * 64 + pb)) * 2560 + wb * 16 + dl0), hp.u);
        }
        barf(gflags, ggen, 64, wb, 2 * tt + 3, amDet);
    }
}

// ================= fallback per-step kernels (validated) =================
__global__ __launch_bounds__(64) void enc_step_mfma(
    const _Float16* __restrict__ Wenc16, const _Float16* __restrict__ emb_src16,
    _Float16* __restrict__ h16_enc, float* __restrict__ c_enc,
    const float* __restrict__ bf, const float* __restrict__ bb,
    _Float16* __restrict__ enc_out16, int s)
{
    __shared__ float gbuf[16 * 66];
    const int lane = threadIdx.x;
    const int blk = blockIdx.x;
    const int dir = blk >> 7, tile = blk & 127;
    const int par = s & 1;
    const int s_eff = dir ? (SLEN - 1 - s) : s;
    const int r16 = lane & 15, kg = lane >> 4;

    const _Float16* Bw = Wenc16 + ((size_t)(dir * 2048 + tile * 16 + r16)) * 1024 + kg * 8;
    const _Float16* Ax = emb_src16 + ((size_t)(s_eff * 64 + r16)) * 512 + kg * 8;
    const _Float16* Ah = h16_enc + ((size_t)((par * 2 + dir) * 64 + r16)) * 512 + kg * 8;

    f32x4 acc[4] = {};
    #pragma unroll 4
    for (int kc = 0; kc < 16; ++kc) {
        f16x8 bfr = *(const f16x8*)(Bw + kc * 32);
        #pragma unroll
        for (int m = 0; m < 4; ++m) {
            f16x8 a = *(const f16x8*)(Ax + kc * 32 + (size_t)m * 16 * 512);
            acc[m] = __builtin_amdgcn_mfma_f32_16x16x32_f16(a, bfr, acc[m], 0, 0, 0);
        }
    }
    #pragma unroll 4
    for (int kc = 0; kc < 16; ++kc) {
        f16x8 bfr = *(const f16x8*)(Bw + 512 + kc * 32);
        #pragma unroll
        for (int m = 0; m < 4; ++m) {
            f16x8 a = *(const f16x8*)(Ah + kc * 32 + (size_t)m * 16 * 512);
            acc[m] = __builtin_amdgcn_mfma_f32_16x16x32_f16(a, bfr, acc[m], 0, 0, 0);
        }
    }
    #pragma unroll
    for (int m = 0; m < 4; ++m)
        #pragma unroll
        for (int rI = 0; rI < 4; ++rI)
            gbuf[r16 * 66 + m * 16 + kg * 4 + rI] = acc[m][rI];
    __syncthreads();

    const float* bias = dir ? bb : bf;
    const int b = lane;
    #pragma unroll
    for (int dl = 0; dl < 4; ++dl) {
        const int d = tile * 4 + dl;
        float g0 = gbuf[(dl * 4 + 0) * 66 + b] + bias[d];
        float g1 = gbuf[(dl * 4 + 1) * 66 + b] + bias[512 + d];
        float g2 = gbuf[(dl * 4 + 2) * 66 + b] + bias[1024 + d];
        float g3 = gbuf[(dl * 4 + 3) * 66 + b] + bias[1536 + d];
        const size_t cur = ((size_t)(par * 2 + dir) * 64 + b) * 512 + d;
        const size_t nxt = ((size_t)((par ^ 1) * 2 + dir) * 64 + b) * 512 + d;
        float c2 = sigmoidf_(g1) * c_enc[cur] + sigmoidf_(g0) * tanhf_(g2);
        float h2 = sigmoidf_(g3) * tanhf_(c2);
        c_enc[nxt] = c2;
        h16_enc[nxt] = (_Float16)h2;
        enc_out16[((size_t)s_eff * 64 + b) * 1024 + dir * 512 + d] = (_Float16)h2;
    }
}

__global__ __launch_bounds__(256) void dec_init(
    const _Float16* __restrict__ enc_out16, const float* __restrict__ c_enc,
    _Float16* __restrict__ predA, float* __restrict__ c_dec)
{
    int idx = blockIdx.x * 256 + threadIdx.x;
    int b = (idx >> 10) & 63, d = idx & 1023;
    if (idx < 65536) {
        _Float16 v = (d < 512) ? enc_out16[(size_t)(127 * 64 + b) * 1024 + d]
                               : enc_out16[(size_t)(0 * 64 + b) * 1024 + d];
        predA[(size_t)b * 2560 + d] = v;
    } else {
        float v = (d < 512) ? c_enc[((size_t)(0 * 2 + 0) * 64 + b) * 512 + d]
                            : c_enc[((size_t)(0 * 2 + 1) * 64 + b) * 512 + (d - 512)];
        c_dec[(size_t)b * 1024 + d] = v;
    }
}

__global__ __launch_bounds__(64) void hatt_mfma(
    const _Float16* __restrict__ predA, const _Float16* __restrict__ Wa16,
    float* __restrict__ hatt, int t)
{
    const int lane = threadIdx.x;
    const int tile = blockIdx.x;
    const int r16 = lane & 15, kg = lane >> 4;
    const _Float16* Ap = predA + ((size_t)(t * 64 + r16)) * 2560 + kg * 8;
    const _Float16* Bw = Wa16 + ((size_t)(tile * 16 + r16)) * 1024 + kg * 8;
    f32x4 acc[4] = {};
    #pragma unroll 4
    for (int kc = 0; kc < 32; ++kc) {
        f16x8 bfr = *(const f16x8*)(Bw + kc * 32);
        #pragma unroll
        for (int m = 0; m < 4; ++m) {
            f16x8 a = *(const f16x8*)(Ap + kc * 32 + (size_t)m * 16 * 2560);
            acc[m] = __builtin_amdgcn_mfma_f32_16x16x32_f16(a, bfr, acc[m], 0, 0, 0);
        }
    }
    #pragma unroll
    for (int m = 0; m < 4; ++m)
        #pragma unroll
        for (int rI = 0; rI < 4; ++rI)
            hatt[(size_t)(m * 16 + kg * 4 + rI) * 256 + tile * 16 + r16] = acc[m][rI];
}

__global__ __launch_bounds__(256) void attn_step(
    const int* __restrict__ src, const float* __restrict__ hatt, const float* __restrict__ vvec,
    const _Float16* __restrict__ enc_part16, const _Float16* __restrict__ enc_out16,
    _Float16* __restrict__ predA, int t)
{
    __shared__ float ha[256], sv[256], sc[128], red[128];
    const int b = blockIdx.x, tid = threadIdx.x;
    ha[tid] = hatt[b * 256 + tid];
    sv[tid] = vvec[tid];
    __syncthreads();
    if (tid < 128) {
        const f16x8* ep = (const f16x8*)(enc_part16 + ((size_t)tid * 64 + b) * 256);
        float acc = 0.f;
        #pragma unroll 4
        for (int j8 = 0; j8 < 32; ++j8) {
            f16x8 e = ep[j8];
            #pragma unroll
            for (int u = 0; u < 8; ++u)
                acc += tanhf_(ha[j8 * 8 + u] + (float)e[u]) * sv[j8 * 8 + u];
        }
        float scv = (src[tid * 64 + b] != 0) ? acc : -1e10f;
        sc[tid] = scv; red[tid] = scv;
    }
    __syncthreads();
    for (int off = 64; off > 0; off >>= 1) { if (tid < off) red[tid] = fmaxf(red[tid], red[tid + off]); __syncthreads(); }
    const float mx = red[0];
    __syncthreads();
    if (tid < 128) { float e = __expf(sc[tid] - mx); sc[tid] = e; red[tid] = e; }
    __syncthreads();
    for (int off = 64; off > 0; off >>= 1) { if (tid < off) red[tid] += red[tid + off]; __syncthreads(); }
    const float inv = 1.0f / red[0];
    __syncthreads();

    float a0 = 0.f, a1 = 0.f, a2 = 0.f, a3 = 0.f;
    for (int sI = 0; sI < 128; ++sI) {
        float as = sc[sI] * inv;
        f16x4 ev = *(const f16x4*)(enc_out16 + ((size_t)sI * 64 + b) * 1024 + tid * 4);
        a0 += as * (float)ev[0]; a1 += as * (float)ev[1];
        a2 += as * (float)ev[2]; a3 += as * (float)ev[3];
    }
    f16x4 o = { (_Float16)a0, (_Float16)a1, (_Float16)a2, (_Float16)a3 };
    *(f16x4*)(predA + ((size_t)(64 + t * 64 + b)) * 2560 + 1024 + tid * 4) = o;
}

__global__ __launch_bounds__(64) void dec_gates(
    const _Float16* __restrict__ Wd16, const float* __restrict__ bd,
    float* __restrict__ c_dec, _Float16* __restrict__ predA, int t)
{
    __shared__ float gbuf[16 * 66];
    const int lane = threadIdx.x;
    const int tile = blockIdx.x;
    const int par = t & 1;
    const int r16 = lane & 15, kg = lane >> 4;
    const _Float16* Bw = Wd16 + ((size_t)(tile * 16 + r16)) * 2560 + kg * 8;
    const _Float16* At = predA + ((size_t)(64 + t * 64 + r16)) * 2560 + kg * 8;
    const _Float16* Ah = predA + ((size_t)(t * 64 + r16)) * 2560 + kg * 8;
    f32x4 acc[4] = {};
    #pragma unroll 4
    for (int kc = 0; kc < 16; ++kc) {
        f16x8 bfr = *(const f16x8*)(Bw + kc * 32);
        #pragma unroll
        for (int m = 0; m < 4; ++m) {
            f16x8 a = *(const f16x8*)(At + 2048 + kc * 32 + (size_t)m * 16 * 2560);
            acc[m] = __builtin_amdgcn_mfma_f32_16x16x32_f16(a, bfr, acc[m], 0, 0, 0);
        }
    }
    #pragma unroll 4
    for (int kc = 0; kc < 32; ++kc) {
        f16x8 bfr = *(const f16x8*)(Bw + 512 + kc * 32);
        #pragma unroll
        for (int m = 0; m < 4; ++m) {
            f16x8 a = *(const f16x8*)(At + 1024 + kc * 32 + (size_t)m * 16 * 2560);
            acc[m] = __builtin_amdgcn_mfma_f32_16x16x32_f16(a, bfr, acc[m], 0, 0, 0);
        }
    }
    #pragma unroll 4
    for (int kc = 0; kc < 32; ++kc) {
        f16x8 bfr = *(const f16x8*)(Bw + 1536 + kc * 32);
        #pragma unroll
        for (int m = 0; m < 4; ++m) {
            f16x8 a = *(const f16x8*)(Ah + kc * 32 + (size_t)m * 16 * 2560);
            acc[m] = __builtin_amdgcn_mfma_f32_16x16x32_f16(a, bfr, acc[m], 0, 0, 0);
        }
    }
    #pragma unroll
    for (int m = 0; m < 4; ++m)
        #pragma unroll
        for (int rI = 0; rI < 4; ++rI)
            gbuf[r16 * 66 + m * 16 + kg * 4 + rI] = acc[m][rI];
    __syncthreads();

    const int b = lane;
    #pragma unroll
    for (int dl = 0; dl < 4; ++dl) {
        const int d = tile * 4 + dl;
        float g0 = gbuf[(dl * 4 + 0) * 66 + b] + bd[d];
        float g1 = gbuf[(dl * 4 + 1) * 66 + b] + bd[1024 + d];
        float g2 = gbuf[(dl * 4 + 2) * 66 + b] + bd[2048 + d];
        float g3 = gbuf[(dl * 4 + 3) * 66 + b] + bd[3072 + d];
        float c2 = sigmoidf_(g1) * c_dec[(size_t)(par * 64 + b) * 1024 + d] + sigmoidf_(g0) * tanhf_(g2);
        float h2 = sigmoidf_(g3) * tanhf_(c2);
        c_dec[(size_t)((par ^ 1) * 64 + b) * 1024 + d] = c2;
        predA[((size_t)(64 + t * 64 + b)) * 2560 + d] = (_Float16)h2;
    }
}

// ================= generic fp16-A MFMA GEMM =================
__global__ __launch_bounds__(256, 2) void gemm_a16(
    const _Float16* __restrict__ A, int lda,
    const float* __restrict__ B, int ldb,
    const float* __restrict__ bias,
    void* __restrict__ Cv, int ldc, int K, int Mvalid, int ntn, int c16)
{
    __shared__ _Float16 As[8192];
    __shared__ _Float16 Bs[8192];

    const int nwg = gridDim.x;
    const int id = blockIdx.x;
    const int q = nwg >> 3, r = nwg & 7;
    const int xcd = id & 7, ix = id >> 3;
    const int wg = (xcd < r) ? (xcd * (q + 1) + ix) : (r * (q + 1) + (xcd - r) * q + ix);
    const int per = ntn << 3;
    const int g = wg / per, rem = wg % per;
    const int mt = g * 8 + (rem & 7), nt = rem >> 3;

    const int t = threadIdx.x, lane = t & 63, wid = t >> 6;
    const int wr = wid >> 1, wc = wid & 1;

    const int arow_s = t >> 3, ac8 = t & 7;
    const int brow_s = t >> 4, bc4 = t & 15;
    const _Float16* Ap = A + (size_t)(mt * 128 + arow_s) * lda + ac8 * 8;
    const float*    Bp = B + (size_t)(nt * 128 + brow_s) * ldb + bc4 * 4;
    const int awx = (ac8 * 8) ^ ((arow_s & 7) << 3);
    const int bwx = (bc4 * 4) ^ ((brow_s & 7) << 3);

    const int kts = K >> 6;
    f32x4 acc[4][4] = {};
    f16x8 ra[4]; float4 rb[8];
    #pragma unroll
    for (int i = 0; i < 4; ++i) ra[i] = *(const f16x8*)(Ap + (size_t)i * 32 * lda);
    #pragma unroll
    for (int i = 0; i < 8; ++i) rb[i] = *(const float4*)(Bp + (size_t)i * 16 * ldb);

    const int abase = (wr * 64 + (lane & 15)) * 64 + (lane >> 4) * 8;
    const int bbase = (wc * 64 + (lane & 15)) * 64 + (lane >> 4) * 8;
    const int sxor = (lane & 7) << 3;

    for (int kt = 0; kt < kts; ++kt) {
        f16x4 cb[8];
        #pragma unroll
        for (int i = 0; i < 8; ++i)
            cb[i] = (f16x4){(_Float16)rb[i].x, (_Float16)rb[i].y, (_Float16)rb[i].z, (_Float16)rb[i].w};
        __syncthreads();
        #pragma unroll
        for (int i = 0; i < 4; ++i)
            *(f16x8*)&As[(arow_s + i * 32) * 64 + awx] = ra[i];
        #pragma unroll
        for (int i = 0; i < 8; ++i)
            *(f16x4*)&Bs[(brow_s + i * 16) * 64 + bwx] = cb[i];
        __syncthreads();
        if (kt + 1 < kts) {
            #pragma unroll
            for (int i = 0; i < 4; ++i) ra[i] = *(const f16x8*)(Ap + (size_t)i * 32 * lda + (kt + 1) * 64);
            #pragma unroll
            for (int i = 0; i < 8; ++i) rb[i] = *(const float4*)(Bp + (size_t)i * 16 * ldb + (kt + 1) * 64);
        }
        #pragma unroll
        for (int kk = 0; kk < 2; ++kk) {
            f16x8 af[4], bfr[4];
            #pragma unroll
            for (int m = 0; m < 4; ++m) af[m]  = *(const f16x8*)&As[(abase + m * 16 * 64 + kk * 32) ^ sxor];
            #pragma unroll
            for (int n = 0; n < 4; ++n) bfr[n] = *(const f16x8*)&Bs[(bbase + n * 16 * 64 + kk * 32) ^ sxor];
            #pragma unroll
            for (int m = 0; m < 4; ++m)
                #pragma unroll
                for (int n = 0; n < 4; ++n)
                    acc[m][n] = __builtin_amdgcn_mfma_f32_16x16x32_f16(af[m], bfr[n], acc[m][n], 0, 0, 0);
        }
    }

    const int ccol = nt * 128 + wc * 64 + (lane & 15);
    const int crow0 = mt * 128 + wr * 64 + ((lane >> 4) << 2);
    float bv[4];
    #pragma unroll
    for (int n = 0; n < 4; ++n) bv[n] = bias[ccol + n * 16];
    #pragma unroll
    for (int m = 0; m < 4; ++m) {
        #pragma unroll
        for (int rI = 0; rI < 4; ++rI) {
            const int row = crow0 + m * 16 + rI;
            if (row < Mvalid) {
                if (c16) {
                    _Float16* C = (_Float16*)Cv;
                    #pragma unroll
                    for (int n = 0; n < 4; ++n)
                        C[(size_t)row * ldc + ccol + n * 16] = (_Float16)(acc[m][n][rI] + bv[n]);
                } else {
                    float* C = (float*)Cv;
                    #pragma unroll
                    for (int n = 0; n < 4; ++n)
                        C[(size_t)row * ldc + ccol + n * 16] = acc[m][n][rI] + bv[n];
                }
            }
        }
    }
}

// ================= launch =================
extern "C" void kernel_launch(void* const* d_in, const int* in_sizes, int n_in,
                              void* d_out, int out_size, void* d_ws, size_t ws_size,
                              hipStream_t stream) {
    const int*   src     = (const int*)d_in[0];
    const int*   trg     = (const int*)d_in[1];
    const float* enc_emb = (const float*)d_in[2];
    const float* Wf_ih   = (const float*)d_in[3];
    const float* Wf_hh   = (const float*)d_in[4];
    const float* bf      = (const float*)d_in[5];
    const float* Wb_ih   = (const float*)d_in[6];
    const float* Wb_hh   = (const float*)d_in[7];
    const float* bb      = (const float*)d_in[8];
    const float* Wa      = (const float*)d_in[9];
    const float* ba      = (const float*)d_in[10];
    const float* vvec    = (const float*)d_in[11];
    const float* dec_emb = (const float*)d_in[12];
    const float* Wd_ih   = (const float*)d_in[13];
    const float* Wd_hh   = (const float*)d_in[14];
    const float* bd      = (const float*)d_in[15];
    const float* Wo      = (const float*)d_in[16];
    const float* bo      = (const float*)d_in[17];
    float* out = (float*)d_out;

    char* w = (char*)d_ws;
    _Float16* Wenc16     = (_Float16*)(w);               // 8,388,608 B
    _Float16* Wd16       = (_Float16*)(w + 8388608);     // 20,971,520 B
    _Float16* Wa16       = (_Float16*)(w + 29360128);    // 524,288 B
    _Float16* emb_src16  = (_Float16*)(w + 29884416);    // 8,388,608 B
    _Float16* enc_out16  = (_Float16*)(w + 38273024);    // 16,777,216 B
    _Float16* predA      = (_Float16*)(w + 55050240);    // 21,299,200 B (4160 x 2560)
    _Float16* h16_enc    = (_Float16*)(w + 76349440);    // 262,144 B
    float*    c_enc      = (float*)   (w + 76611584);    // 524,288 B
    float*    c_dec      = (float*)   (w + 77135872);    // 524,288 B
    float*    hatt       = (float*)   (w + 77660160);    // 65,536 B
    _Float16* enc_part16 = (_Float16*)(w + 77725696);    // 4,194,304 B
    int*      bar_ws     = (int*)     (w + 81920000);    // 1,331,200 B: 325 slots x 4KB
    const size_t need_bytes = 83251200;
    if (ws_size < need_bytes) return;

    init_convert<<<92628, 256, 0, stream>>>(
        src, trg, enc_emb, dec_emb, Wf_ih, Wf_hh, Wb_ih, Wb_hh, Wa, Wd_ih, Wd_hh,
        out, Wenc16, Wd16, Wa16, emb_src16, predA, c_enc, h16_enc, bar_ws);

    // ---- encoder (cooperative, 4 independent 64-block groups; fallback per-step) ----
    {
        const _Float16* a0 = Wenc16; const _Float16* a1 = emb_src16;
        _Float16* a2 = h16_enc; float* a3 = c_enc;
        const float* a4 = bf; const float* a5 = bb;
        _Float16* a6 = enc_out16; int* a7 = bar_ws;
        void* args[] = { &a0, &a1, &a2, &a3, &a4, &a5, &a6, &a7 };
        hipError_t e = hipLaunchCooperativeKernel((const void*)enc_coop, dim3(256), dim3(256), args, 0, stream);
        if (e != hipSuccess) {
            for (int s = 0; s < SLEN; ++s)
                enc_step_mfma<<<256, 64, 0, stream>>>(Wenc16, emb_src16, h16_enc, c_enc, bf, bb, enc_out16, s);
        }
    }

    // enc_part16 = enc_out16 @ Wa[:,1024:]^T + ba
    gemm_a16<<<128, 256, 0, stream>>>(enc_out16, 1024, Wa + 1024, 2048, ba,
                                      enc_part16, 256, 1024, 8192, 2, 1);

    // ---- decoder (cooperative, 64 blocks x 512 thr; fallback per-step) ----
    {
        const _Float16* a0 = Wd16; const _Float16* a1 = Wa16;
        const float* a2 = bd; const float* a3 = vvec;
        const int* a4 = src; const _Float16* a5 = enc_part16;
        const _Float16* a6 = enc_out16; const float* a7 = c_enc;
        _Float16* a8 = predA; int* a9 = bar_ws;
        void* args[] = { &a0, &a1, &a2, &a3, &a4, &a5, &a6, &a7, &a8, &a9 };
        hipError_t e = hipLaunchCooperativeKernel((const void*)dec_coop, dim3(64), dim3(512), args, 0, stream);
        if (e != hipSuccess) {
            dec_init<<<512, 256, 0, stream>>>(enc_out16, c_enc, predA, c_dec);
            for (int t = 0; t < TSTEPS; ++t) {
                hatt_mfma<<<16, 64, 0, stream>>>(predA, Wa16, hatt, t);
                attn_step<<<64, 256, 0, stream>>>(src, hatt, vvec, enc_part16, enc_out16, predA, t);
                dec_gates<<<256, 64, 0, stream>>>(Wd16, bd, c_dec, predA, t);
            }
        }
    }

    // out[64.. , :] = predA[64..] @ Wo^T + bo
    gemm_a16<<<8000, 256, 0, stream>>>(predA + (size_t)64 * 2560, 2560, Wo, 2560, bo,
                                       out + (size_t)64 * VOC, VOC, 2560, 4032, 250, 0);
}

// Round 10
// 6227.775 us; speedup vs baseline: 1.1027x; 1.1027x over previous
//
#include <hip/hip_runtime.h>

#define SLEN  128
#define BATCH 64
#define EMB   512
#define HID   512
#define DDEC  1024
#define ATT   256
#define VOC   32000
#define TSTEPS 63
#define SLOT  1024   // ints per 4KB slot

typedef _Float16 f16x4 __attribute__((ext_vector_type(4)));
typedef _Float16 f16x8 __attribute__((ext_vector_type(8)));
typedef float    f32x4 __attribute__((ext_vector_type(4)));

union HQ  { unsigned long long q[2]; f16x8 v; };
union HP  { _Float16 h[2]; unsigned u; };
union HP4 { _Float16 h[4]; f16x4 v4; unsigned long long u; };

__device__ __forceinline__ float sigmoidf_(float x) { return 1.0f / (1.0f + __expf(-x)); }
__device__ __forceinline__ float tanhf_(float x)    { return 1.0f - 2.0f / (__expf(2.0f * x) + 1.0f); }

__device__ __forceinline__ void st_u32(void* p, unsigned v) {
    __hip_atomic_store((unsigned*)p, v, __ATOMIC_RELAXED, __HIP_MEMORY_SCOPE_AGENT);
}
__device__ __forceinline__ void st_u64(void* p, unsigned long long v) {
    __hip_atomic_store((unsigned long long*)p, v, __ATOMIC_RELAXED, __HIP_MEMORY_SCOPE_AGENT);
}
__device__ __forceinline__ unsigned long long ld_u64(const void* p) {
    return __hip_atomic_load((const unsigned long long*)p, __ATOMIC_RELAXED, __HIP_MEMORY_SCOPE_AGENT);
}
__device__ __forceinline__ void st_i32(int* p, int v) {
    __hip_atomic_store(p, v, __ATOMIC_RELAXED, __HIP_MEMORY_SCOPE_AGENT);
}
__device__ __forceinline__ int ld_i32(const int* p) {
    return __hip_atomic_load(p, __ATOMIC_RELAXED, __HIP_MEMORY_SCOPE_AGENT);
}

// ---- detector-free barrier: arrival = 1 relaxed store; wave-0 polls all flags.
__device__ __forceinline__ void bar_arrive(int* flags, int myid, int epoch) {
    __syncthreads();                       // drains this block's data stores (vmcnt 0)
    if (threadIdx.x == 0) st_i32(flags + myid * SLOT, epoch);
}
__device__ __forceinline__ void bar_wait(int* flags, int nf, int epoch) {
    if ((int)threadIdx.x < 64) {
        bool done = false;
        while (!done) {
            bool ok = true;
            for (int i = threadIdx.x; i < nf; i += 64)
                ok = ok && (ld_i32(flags + i * SLOT) >= epoch);
            done = __all(ok);
            if (!done) __builtin_amdgcn_s_sleep(1);
        }
    }
    __syncthreads();
}

// ================= init =================
__global__ __launch_bounds__(256) void init_convert(
    const int* __restrict__ src, const int* __restrict__ trg,
    const float* __restrict__ enc_emb, const float* __restrict__ dec_emb,
    const float* __restrict__ Wf_ih, const float* __restrict__ Wf_hh,
    const float* __restrict__ Wb_ih, const float* __restrict__ Wb_hh,
    const float* __restrict__ Wa, const float* __restrict__ Wd_ih, const float* __restrict__ Wd_hh,
    float* __restrict__ out0,
    _Float16* __restrict__ Wenc16, _Float16* __restrict__ Wd16, _Float16* __restrict__ Wa16,
    _Float16* __restrict__ emb_src16, _Float16* __restrict__ predA,
    float* __restrict__ c_enc, _Float16* __restrict__ h16_enc, int* __restrict__ bar_ws)
{
    long idx = (long)blockIdx.x * 256 + threadIdx.x;
    if (idx < 2048000L) { out0[idx] = 0.f; return; }
    idx -= 2048000L;
    if (idx < 4194304L) {   // Wenc16 [dir][2048][1024]
        int dir = (int)(idx >> 21);
        int rem = (int)(idx & ((1 << 21) - 1));
        int rr = rem >> 10, c = rem & 1023;
        int d = rr >> 2, qg = rr & 3;
        const float* Wih = dir ? Wb_ih : Wf_ih;
        const float* Whh = dir ? Wb_hh : Wf_hh;
        float v = (c < 512) ? Wih[(long)(qg * 512 + d) * 512 + c]
                            : Whh[(long)(qg * 512 + d) * 512 + (c - 512)];
        Wenc16[idx] = (_Float16)v; return;
    }
    idx -= 4194304L;
    if (idx < 10485760L) {  // Wd16 [4096][2560]
        int rr = (int)(idx / 2560), c = (int)(idx % 2560);
        int d = rr >> 2, qg = rr & 3;
        float v = (c < 1536) ? Wd_ih[(long)(qg * 1024 + d) * 1536 + c]
                             : Wd_hh[(long)(qg * 1024 + d) * 1024 + (c - 1536)];
        Wd16[idx] = (_Float16)v; return;
    }
    idx -= 10485760L;
    if (idx < 262144L) {    // Wa16 [256][1024]
        int rr = (int)(idx >> 10), c = (int)(idx & 1023);
        Wa16[idx] = (_Float16)Wa[(long)rr * 2048 + c]; return;
    }
    idx -= 262144L;
    if (idx < 4194304L) {   // emb_src16
        int sb = (int)(idx >> 9), e = (int)(idx & 511);
        int tok = src[sb];
        emb_src16[idx] = (_Float16)enc_emb[(long)tok * 512 + e]; return;
    }
    idx -= 4194304L;
    if (idx < 2064384L) {   // predA emb cols
        int rI = (int)(idx >> 9), e = (int)(idx & 511);
        int tok = trg[rI];
        predA[(long)(64 + rI) * 2560 + 2048 + e] = (_Float16)dec_emb[(long)tok * 512 + e]; return;
    }
    idx -= 2064384L;
    if (idx < 65536L) { c_enc[idx] = 0.f; return; }
    idx -= 65536L;
    if (idx < 65536L) { h16_enc[idx] = (_Float16)0.f; return; }
    idx -= 65536L;
    if (idx < 655360L) { bar_ws[idx] = 0; }   // 640 slots x 1024 ints
}

// ================= cooperative encoder: 4 groups (dir x batch-half) x 64 blocks x 256 thr =================
// Weights in LDS; A-fragments loaded DIRECTLY from global (no LDS staging).
__global__ __launch_bounds__(256, 1) void enc_coop(
    const _Float16* __restrict__ Wenc16, const _Float16* __restrict__ emb_src16,
    _Float16* __restrict__ h16_enc, float* __restrict__ c_enc,
    const float* __restrict__ bf, const float* __restrict__ bb,
    _Float16* __restrict__ enc_out16, int* __restrict__ bar_ws)
{
    __shared__ _Float16 Wl[32768];       // 64KB [kc32][gt2][512]
    __shared__ float gbuf[32][34];

    const int t = threadIdx.x, lane = t & 63, wv = t >> 6;
    const int blk = blockIdx.x;
    const int g = blk >> 6, wb = blk & 63;
    const int dir = g >> 1, bh = g & 1;
    const int r16 = lane & 15, kg = lane >> 4;
    int* eflags = bar_ws + (384 + g * 64) * SLOT;

    #pragma unroll
    for (int i = 0; i < 16; ++i) {
        int h0 = (i * 256 + t) * 8;
        int kc = h0 >> 10;
        int rem = h0 & 1023;
        int gt2 = rem >> 9, l = (rem >> 3) & 63;
        f16x8 v = *(const f16x8*)(Wenc16 +
            ((size_t)(dir * 2048 + wb * 32 + gt2 * 16 + (l & 15))) * 1024 + (l >> 4) * 8 + kc * 32);
        *(f16x8*)&Wl[h0] = v;
    }

    const float* bias = dir ? bb : bf;
    const int pb = t & 31, dp = t >> 5;       // pointwise: t<128 -> dp 0..3
    const int dl0 = dp * 2;
    float bias2[2][4], creg2[2] = {0.f, 0.f};
    if (t < 128) {
        #pragma unroll
        for (int j = 0; j < 2; ++j)
            #pragma unroll
            for (int q = 0; q < 4; ++q)
                bias2[j][q] = bias[q * 512 + wb * 8 + dl0 + j];
    }
    __syncthreads();

    for (int s = 0; s < SLEN; ++s) {
        const int par = s & 1;
        const int s_eff = dir ? (127 - s) : s;
        const int gt = wv & 1, mb = wv >> 1;
        const int arow = bh * 32 + mb * 16 + r16;
        const _Float16* Ax = emb_src16 + ((size_t)(s_eff * 64 + arow)) * 512 + kg * 8;
        const unsigned long long* Hq =
            (const unsigned long long*)(h16_enc + ((size_t)((par * 2 + dir) * 64 + arow)) * 512);
        f32x4 acc = {};
        #pragma unroll 4
        for (int kc = 0; kc < 16; ++kc) {
            f16x8 bw = *(const f16x8*)&Wl[kc * 1024 + gt * 512 + lane * 8];
            f16x8 a  = *(const f16x8*)(Ax + kc * 32);
            acc = __builtin_amdgcn_mfma_f32_16x16x32_f16(a, bw, acc, 0, 0, 0);
        }
        #pragma unroll 4
        for (int kc = 0; kc < 16; ++kc) {
            f16x8 bw = *(const f16x8*)&Wl[(16 + kc) * 1024 + gt * 512 + lane * 8];
            HQ hq;
            hq.q[0] = ld_u64(Hq + kc * 8 + kg * 2);
            hq.q[1] = ld_u64(Hq + kc * 8 + kg * 2 + 1);
            acc = __builtin_amdgcn_mfma_f32_16x16x32_f16(hq.v, bw, acc, 0, 0, 0);
        }
        // C/D: col=lane&15 -> gate row, row=kg*4+rI -> batch
        #pragma unroll
        for (int rI = 0; rI < 4; ++rI)
            gbuf[gt * 16 + (lane & 15)][mb * 16 + kg * 4 + rI] = acc[rI];
        __syncthreads();
        if (t < 128) {
            HP hp;
            #pragma unroll
            for (int j = 0; j < 2; ++j) {
                const int dl = dl0 + j;
                float g0 = gbuf[dl * 4 + 0][pb] + bias2[j][0];
                float g1 = gbuf[dl * 4 + 1][pb] + bias2[j][1];
                float g2 = gbuf[dl * 4 + 2][pb] + bias2[j][2];
                float g3 = gbuf[dl * 4 + 3][pb] + bias2[j][3];
                float c2 = sigmoidf_(g1) * creg2[j] + sigmoidf_(g0) * tanhf_(g2);
                float h2 = sigmoidf_(g3) * tanhf_(c2);
                creg2[j] = c2;
                hp.h[j] = (_Float16)h2;
            }
            const int bglob = bh * 32 + pb;
            const int d0 = wb * 8 + dl0;
            st_u32((void*)(h16_enc + ((size_t)((par ^ 1) * 2 + dir) * 64 + bglob) * 512 + d0), hp.u);
            *(unsigned*)(enc_out16 + ((size_t)s_eff * 64 + bglob) * 1024 + dir * 512 + d0) = hp.u;
        }
        bar_arrive(eflags, wb, s + 1);
        bar_wait(eflags, 64, s + 1);
    }
    if (t < 128) {
        const int bglob = bh * 32 + pb;
        const int d0 = wb * 8 + dl0;
        c_enc[((size_t)dir * 64 + bglob) * 512 + d0] = creg2[0];
        c_enc[((size_t)dir * 64 + bglob) * 512 + d0 + 1] = creg2[1];
    }
}

// ================= cooperative decoder: 320 blocks x 256 thr =================
// Blocks 0-63: attention (batch = blk). Blocks 64-319: gates (16 Wd rows each, L2-resident).
// Gates overlap emb+h K-segments with attention; only ctx segment waits on cf barrier.
__global__ __launch_bounds__(256, 1) void dec_coop(
    const _Float16* __restrict__ Wd16, const _Float16* __restrict__ Wa16,
    const float* __restrict__ bd, const float* __restrict__ vvec,
    const int* __restrict__ src, const _Float16* __restrict__ enc_part16,
    const _Float16* __restrict__ enc_out16, const float* __restrict__ c_enc,
    _Float16* __restrict__ predA, int* __restrict__ bar_ws)
{
    __shared__ float gbuf[16][68];
    __shared__ float ha[256], sv[256], sc[128], esum[256], red[4];

    const int t = threadIdx.x, lane = t & 63, wv = t >> 6;
    const int r16 = lane & 15, kg = lane >> 4;
    const int blk = blockIdx.x;
    int* cf  = bar_ws;               // 64 ctx flags
    int* hs  = bar_ws + 64 * SLOT;   // 256 h flags
    int* hf0 = bar_ws + 320 * SLOT;  // 64 h0 flags

    if (blk < 64) {
        // ===== attention block, batch wb =====
        const int wb = blk;
        sv[t] = vvec[t];
        {   // h0 for batch wb -> predA row wb (4 halves per thread)
            const int d0 = t * 4;
            const size_t rbase = (d0 < 512) ? (size_t)(127 * 64 + wb) * 1024
                                            : (size_t)(0 * 64 + wb) * 1024;
            HP4 o;
            o.h[0] = enc_out16[rbase + d0];
            o.h[1] = enc_out16[rbase + d0 + 1];
            o.h[2] = enc_out16[rbase + d0 + 2];
            o.h[3] = enc_out16[rbase + d0 + 3];
            st_u64((void*)(predA + (size_t)wb * 2560 + d0), o.u);
        }
        bar_arrive(hf0, wb, 1);
        for (int tt = 0; tt < TSTEPS; ++tt) {
            if (tt == 0) bar_wait(hf0, 64, 1); else bar_wait(hs, 256, tt);
            // P1: hatt via 16-batch-group MFMA
            {
                const int base_m = wb & 48;
                const _Float16* Ahh = predA + ((size_t)(tt * 64 + base_m + r16)) * 2560 + kg * 8;
                f32x4 acc4[4] = {};
                #pragma unroll 4
                for (int kc = 0; kc < 32; ++kc) {
                    f16x8 a = *(const f16x8*)(Ahh + kc * 32);
                    #pragma unroll
                    for (int jj = 0; jj < 4; ++jj) {
                        f16x8 bw = *(const f16x8*)(Wa16 +
                            ((size_t)((wv * 4 + jj) * 16 + r16)) * 1024 + kg * 8 + kc * 32);
                        acc4[jj] = __builtin_amdgcn_mfma_f32_16x16x32_f16(a, bw, acc4[jj], 0, 0, 0);
                    }
                }
                if (kg == ((wb & 15) >> 2)) {
                    #pragma unroll
                    for (int jj = 0; jj < 4; ++jj)
                        ha[(wv * 4 + jj) * 16 + r16] = acc4[jj][wb & 3];
                }
            }
            __syncthreads();
            // P2: energy (all 256 threads: s = t&127, j-half = t>>7)
            {
                const int s = t & 127, jh = t >> 7;
                const f16x8* ep = (const f16x8*)(enc_part16 + ((size_t)s * 64 + wb) * 256 + jh * 128);
                float acc = 0.f;
                #pragma unroll 2
                for (int j8 = 0; j8 < 16; ++j8) {
                    f16x8 e = ep[j8];
                    #pragma unroll
                    for (int u = 0; u < 8; ++u)
                        acc += tanhf_(ha[jh * 128 + j8 * 8 + u] + (float)e[u]) * sv[jh * 128 + j8 * 8 + u];
                }
                esum[t] = acc;
            }
            __syncthreads();
            if (t < 128) {
                float scv = esum[t] + esum[128 + t];
                scv = (src[t * 64 + wb] != 0) ? scv : -1e10f;
                sc[t] = scv;
                float v = scv;
                #pragma unroll
                for (int off = 32; off > 0; off >>= 1) v = fmaxf(v, __shfl_xor(v, off));
                if (lane == 0) red[t >> 6] = v;
            }
            __syncthreads();
            {
                const float mx = fmaxf(red[0], red[1]);
                if (t < 128) {
                    float e = __expf(sc[t] - mx);
                    sc[t] = e;
                    float v = e;
                    #pragma unroll
                    for (int off = 32; off > 0; off >>= 1) v += __shfl_xor(v, off);
                    if (lane == 0) red[2 + (t >> 6)] = v;
                }
            }
            __syncthreads();
            {
                const float inv = 1.0f / (red[2] + red[3]);
                float a0 = 0.f, a1 = 0.f, a2 = 0.f, a3 = 0.f;
                #pragma unroll 4
                for (int sI = 0; sI < 128; ++sI) {
                    float as = sc[sI] * inv;
                    f16x4 ev = *(const f16x4*)(enc_out16 + ((size_t)sI * 64 + wb) * 1024 + t * 4);
                    a0 += as * (float)ev[0]; a1 += as * (float)ev[1];
                    a2 += as * (float)ev[2]; a3 += as * (float)ev[3];
                }
                HP4 o;
                o.h[0] = (_Float16)a0; o.h[1] = (_Float16)a1;
                o.h[2] = (_Float16)a2; o.h[3] = (_Float16)a3;
                st_u64((void*)(predA + ((size_t)(64 + tt * 64 + wb)) * 2560 + 1024 + t * 4), o.u);
            }
            bar_arrive(cf, wb, tt + 1);
        }
    } else {
        // ===== gate block: rows [gid*16, +16) = d in [gid*4, gid*4+4) =====
        const int gid = blk - 64;
        const int pb = t & 63;
        float bias2[2][4], creg2[2] = {0.f, 0.f};
        if (t < 128) {
            #pragma unroll
            for (int j = 0; j < 2; ++j) {
                const int dg = gid * 4 + (t >> 6) * 2 + j;
                #pragma unroll
                for (int q = 0; q < 4; ++q) bias2[j][q] = bd[q * 1024 + dg];
                creg2[j] = (dg < 512) ? c_enc[(size_t)pb * 512 + dg]
                                      : c_enc[(size_t)(64 + pb) * 512 + (dg - 512)];
            }
        }
        const _Float16* Bbase = Wd16 + (size_t)(gid * 16 + r16) * 2560 + kg * 8;
        for (int tt = 0; tt < TSTEPS; ++tt) {
            if (tt == 0) bar_wait(hf0, 64, 1); else bar_wait(hs, 256, tt);
            const int mb = wv;   // 4 waves = 4 batch tiles of 16
            const _Float16* Ae = predA + ((size_t)(64 + tt * 64 + mb * 16 + r16)) * 2560 + kg * 8;
            const _Float16* Ah = predA + ((size_t)(tt * 64 + mb * 16 + r16)) * 2560 + kg * 8;
            f32x4 acc = {};
            // partial: emb (W cols 0..511) + h (W cols 1536..2559) — no ctx dependency
            #pragma unroll 4
            for (int kc = 0; kc < 16; ++kc) {
                f16x8 bw = *(const f16x8*)(Bbase + kc * 32);
                f16x8 a  = *(const f16x8*)(Ae + 2048 + kc * 32);
                acc = __builtin_amdgcn_mfma_f32_16x16x32_f16(a, bw, acc, 0, 0, 0);
            }
            #pragma unroll 4
            for (int kc = 0; kc < 32; ++kc) {
                f16x8 bw = *(const f16x8*)(Bbase + 1536 + kc * 32);
                f16x8 a  = *(const f16x8*)(Ah + kc * 32);
                acc = __builtin_amdgcn_mfma_f32_16x16x32_f16(a, bw, acc, 0, 0, 0);
            }
            bar_wait(cf, 64, tt + 1);
            // ctx part (W cols 512..1535, A cols 1024..2047)
            #pragma unroll 4
            for (int kc = 0; kc < 32; ++kc) {
                f16x8 bw = *(const f16x8*)(Bbase + 512 + kc * 32);
                f16x8 a  = *(const f16x8*)(Ae + 1024 + kc * 32);
                acc = __builtin_amdgcn_mfma_f32_16x16x32_f16(a, bw, acc, 0, 0, 0);
            }
            // C/D: col=lane&15 -> gate row (N), row=kg*4+rI -> batch (M)
            #pragma unroll
            for (int rI = 0; rI < 4; ++rI)
                gbuf[lane & 15][mb * 16 + kg * 4 + rI] = acc[rI];
            __syncthreads();
            if (t < 128) {
                HP hp;
                #pragma unroll
                for (int j = 0; j < 2; ++j) {
                    const int dl = (t >> 6) * 2 + j;
                    float g0 = gbuf[dl * 4 + 0][pb] + bias2[j][0];
                    float g1 = gbuf[dl * 4 + 1][pb] + bias2[j][1];
                    float g2 = gbuf[dl * 4 + 2][pb] + bias2[j][2];
                    float g3 = gbuf[dl * 4 + 3][pb] + bias2[j][3];
                    float c2 = sigmoidf_(g1) * creg2[j] + sigmoidf_(g0) * tanhf_(g2);
                    float h2 = sigmoidf_(g3) * tanhf_(c2);
                    creg2[j] = c2;
                    hp.h[j] = (_Float16)h2;
                }
                st_u32((void*)(predA + ((size_t)(64 + tt * 64 + pb)) * 2560 + gid * 4 + (t >> 6) * 2), hp.u);
            }
            bar_arrive(hs, gid, tt + 1);
        }
    }
}

// ================= fallback per-step kernels (validated) =================
__global__ __launch_bounds__(64) void enc_step_mfma(
    const _Float16* __restrict__ Wenc16, const _Float16* __restrict__ emb_src16,
    _Float16* __restrict__ h16_enc, float* __restrict__ c_enc,
    const float* __restrict__ bf, const float* __restrict__ bb,
    _Float16* __restrict__ enc_out16, int s)
{
    __shared__ float gbuf[16 * 66];
    const int lane = threadIdx.x;
    const int blk = blockIdx.x;
    const int dir = blk >> 7, tile = blk & 127;
    const int par = s & 1;
    const int s_eff = dir ? (SLEN - 1 - s) : s;
    const int r16 = lane & 15, kg = lane >> 4;

    const _Float16* Bw = Wenc16 + ((size_t)(dir * 2048 + tile * 16 + r16)) * 1024 + kg * 8;
    const _Float16* Ax = emb_src16 + ((size_t)(s_eff * 64 + r16)) * 512 + kg * 8;
    const _Float16* Ah = h16_enc + ((size_t)((par * 2 + dir) * 64 + r16)) * 512 + kg * 8;

    f32x4 acc[4] = {};
    #pragma unroll 4
    for (int kc = 0; kc < 16; ++kc) {
        f16x8 bfr = *(const f16x8*)(Bw + kc * 32);
        #pragma unroll
        for (int m = 0; m < 4; ++m) {
            f16x8 a = *(const f16x8*)(Ax + kc * 32 + (size_t)m * 16 * 512);
            acc[m] = __builtin_amdgcn_mfma_f32_16x16x32_f16(a, bfr, acc[m], 0, 0, 0);
        }
    }
    #pragma unroll 4
    for (int kc = 0; kc < 16; ++kc) {
        f16x8 bfr = *(const f16x8*)(Bw + 512 + kc * 32);
        #pragma unroll
        for (int m = 0; m < 4; ++m) {
            f16x8 a = *(const f16x8*)(Ah + kc * 32 + (size_t)m * 16 * 512);
            acc[m] = __builtin_amdgcn_mfma_f32_16x16x32_f16(a, bfr, acc[m], 0, 0, 0);
        }
    }
    #pragma unroll
    for (int m = 0; m < 4; ++m)
        #pragma unroll
        for (int rI = 0; rI < 4; ++rI)
            gbuf[r16 * 66 + m * 16 + kg * 4 + rI] = acc[m][rI];
    __syncthreads();

    const float* bias = dir ? bb : bf;
    const int b = lane;
    #pragma unroll
    for (int dl = 0; dl < 4; ++dl) {
        const int d = tile * 4 + dl;
        float g0 = gbuf[(dl * 4 + 0) * 66 + b] + bias[d];
        float g1 = gbuf[(dl * 4 + 1) * 66 + b] + bias[512 + d];
        float g2 = gbuf[(dl * 4 + 2) * 66 + b] + bias[1024 + d];
        float g3 = gbuf[(dl * 4 + 3) * 66 + b] + bias[1536 + d];
        const size_t cur = ((size_t)(par * 2 + dir) * 64 + b) * 512 + d;
        const size_t nxt = ((size_t)((par ^ 1) * 2 + dir) * 64 + b) * 512 + d;
        float c2 = sigmoidf_(g1) * c_enc[cur] + sigmoidf_(g0) * tanhf_(g2);
        float h2 = sigmoidf_(g3) * tanhf_(c2);
        c_enc[nxt] = c2;
        h16_enc[nxt] = (_Float16)h2;
        enc_out16[((size_t)s_eff * 64 + b) * 1024 + dir * 512 + d] = (_Float16)h2;
    }
}

__global__ __launch_bounds__(256) void dec_init(
    const _Float16* __restrict__ enc_out16, const float* __restrict__ c_enc,
    _Float16* __restrict__ predA, float* __restrict__ c_dec)
{
    int idx = blockIdx.x * 256 + threadIdx.x;
    int b = (idx >> 10) & 63, d = idx & 1023;
    if (idx < 65536) {
        _Float16 v = (d < 512) ? enc_out16[(size_t)(127 * 64 + b) * 1024 + d]
                               : enc_out16[(size_t)(0 * 64 + b) * 1024 + d];
        predA[(size_t)b * 2560 + d] = v;
    } else {
        float v = (d < 512) ? c_enc[((size_t)(0 * 2 + 0) * 64 + b) * 512 + d]
                            : c_enc[((size_t)(0 * 2 + 1) * 64 + b) * 512 + (d - 512)];
        c_dec[(size_t)b * 1024 + d] = v;
    }
}

__global__ __launch_bounds__(64) void hatt_mfma(
    const _Float16* __restrict__ predA, const _Float16* __restrict__ Wa16,
    float* __restrict__ hatt, int t)
{
    const int lane = threadIdx.x;
    const int tile = blockIdx.x;
    const int r16 = lane & 15, kg = lane >> 4;
    const _Float16* Ap = predA + ((size_t)(t * 64 + r16)) * 2560 + kg * 8;
    const _Float16* Bw = Wa16 + ((size_t)(tile * 16 + r16)) * 1024 + kg * 8;
    f32x4 acc[4] = {};
    #pragma unroll 4
    for (int kc = 0; kc < 32; ++kc) {
        f16x8 bfr = *(const f16x8*)(Bw + kc * 32);
        #pragma unroll
        for (int m = 0; m < 4; ++m) {
            f16x8 a = *(const f16x8*)(Ap + kc * 32 + (size_t)m * 16 * 2560);
            acc[m] = __builtin_amdgcn_mfma_f32_16x16x32_f16(a, bfr, acc[m], 0, 0, 0);
        }
    }
    #pragma unroll
    for (int m = 0; m < 4; ++m)
        #pragma unroll
        for (int rI = 0; rI < 4; ++rI)
            hatt[(size_t)(m * 16 + kg * 4 + rI) * 256 + tile * 16 + r16] = acc[m][rI];
}

__global__ __launch_bounds__(256) void attn_step(
    const int* __restrict__ src, const float* __restrict__ hatt, const float* __restrict__ vvec,
    const _Float16* __restrict__ enc_part16, const _Float16* __restrict__ enc_out16,
    _Float16* __restrict__ predA, int t)
{
    __shared__ float ha[256], sv[256], sc[128], red[128];
    const int b = blockIdx.x, tid = threadIdx.x;
    ha[tid] = hatt[b * 256 + tid];
    sv[tid] = vvec[tid];
    __syncthreads();
    if (tid < 128) {
        const f16x8* ep = (const f16x8*)(enc_part16 + ((size_t)tid * 64 + b) * 256);
        float acc = 0.f;
        #pragma unroll 4
        for (int j8 = 0; j8 < 32; ++j8) {
            f16x8 e = ep[j8];
            #pragma unroll
            for (int u = 0; u < 8; ++u)
                acc += tanhf_(ha[j8 * 8 + u] + (float)e[u]) * sv[j8 * 8 + u];
        }
        float scv = (src[tid * 64 + b] != 0) ? acc : -1e10f;
        sc[tid] = scv; red[tid] = scv;
    }
    __syncthreads();
    for (int off = 64; off > 0; off >>= 1) { if (tid < off) red[tid] = fmaxf(red[tid], red[tid + off]); __syncthreads(); }
    const float mx = red[0];
    __syncthreads();
    if (tid < 128) { float e = __expf(sc[tid] - mx); sc[tid] = e; red[tid] = e; }
    __syncthreads();
    for (int off = 64; off > 0; off >>= 1) { if (tid < off) red[tid] += red[tid + off]; __syncthreads(); }
    const float inv = 1.0f / red[0];
    __syncthreads();

    float a0 = 0.f, a1 = 0.f, a2 = 0.f, a3 = 0.f;
    for (int sI = 0; sI < 128; ++sI) {
        float as = sc[sI] * inv;
        f16x4 ev = *(const f16x4*)(enc_out16 + ((size_t)sI * 64 + b) * 1024 + tid * 4);
        a0 += as * (float)ev[0]; a1 += as * (float)ev[1];
        a2 += as * (float)ev[2]; a3 += as * (float)ev[3];
    }
    f16x4 o = { (_Float16)a0, (_Float16)a1, (_Float16)a2, (_Float16)a3 };
    *(f16x4*)(predA + ((size_t)(64 + t * 64 + b)) * 2560 + 1024 + tid * 4) = o;
}

__global__ __launch_bounds__(64) void dec_gates(
    const _Float16* __restrict__ Wd16, const float* __restrict__ bd,
    float* __restrict__ c_dec, _Float16* __restrict__ predA, int t)
{
    __shared__ float gbuf[16 * 66];
    const int lane = threadIdx.x;
    const int tile = blockIdx.x;
    const int par = t & 1;
    const int r16 = lane & 15, kg = lane >> 4;
    const _Float16* Bw = Wd16 + ((size_t)(tile * 16 + r16)) * 2560 + kg * 8;
    const _Float16* At = predA + ((size_t)(64 + t * 64 + r16)) * 2560 + kg * 8;
    const _Float16* Ah = predA + ((size_t)(t * 64 + r16)) * 2560 + kg * 8;
    f32x4 acc[4] = {};
    #pragma unroll 4
    for (int kc = 0; kc < 16; ++kc) {
        f16x8 bfr = *(const f16x8*)(Bw + kc * 32);
        #pragma unroll
        for (int m = 0; m < 4; ++m) {
            f16x8 a = *(const f16x8*)(At + 2048 + kc * 32 + (size_t)m * 16 * 2560);
            acc[m] = __builtin_amdgcn_mfma_f32_16x16x32_f16(a, bfr, acc[m], 0, 0, 0);
        }
    }
    #pragma unroll 4
    for (int kc = 0; kc < 32; ++kc) {
        f16x8 bfr = *(const f16x8*)(Bw + 512 + kc * 32);
        #pragma unroll
        for (int m = 0; m < 4; ++m) {
            f16x8 a = *(const f16x8*)(At + 1024 + kc * 32 + (size_t)m * 16 * 2560);
            acc[m] = __builtin_amdgcn_mfma_f32_16x16x32_f16(a, bfr, acc[m], 0, 0, 0);
        }
    }
    #pragma unroll 4
    for (int kc = 0; kc < 32; ++kc) {
        f16x8 bfr = *(const f16x8*)(Bw + 1536 + kc * 32);
        #pragma unroll
        for (int m = 0; m < 4; ++m) {
            f16x8 a = *(const f16x8*)(Ah + kc * 32 + (size_t)m * 16 * 2560);
            acc[m] = __builtin_amdgcn_mfma_f32_16x16x32_f16(a, bfr, acc[m], 0, 0, 0);
        }
    }
    #pragma unroll
    for (int m = 0; m < 4; ++m)
        #pragma unroll
        for (int rI = 0; rI < 4; ++rI)
            gbuf[r16 * 66 + m * 16 + kg * 4 + rI] = acc[m][rI];
    __syncthreads();

    const int b = lane;
    #pragma unroll
    for (int dl = 0; dl < 4; ++dl) {
        const int d = tile * 4 + dl;
        float g0 = gbuf[(dl * 4 + 0) * 66 + b] + bd[d];
        float g1 = gbuf[(dl * 4 + 1) * 66 + b] + bd[1024 + d];
        float g2 = gbuf[(dl * 4 + 2) * 66 + b] + bd[2048 + d];
        float g3 = gbuf[(dl * 4 + 3) * 66 + b] + bd[3072 + d];
        float c2 = sigmoidf_(g1) * c_dec[(size_t)(par * 64 + b) * 1024 + d] + sigmoidf_(g0) * tanhf_(g2);
        float h2 = sigmoidf_(g3) * tanhf_(c2);
        c_dec[(size_t)((par ^ 1) * 64 + b) * 1024 + d] = c2;
        predA[((size_t)(64 + t * 64 + b)) * 2560 + d] = (_Float16)h2;
    }
}

// ================= generic fp16-A MFMA GEMM =================
__global__ __launch_bounds__(256, 2) void gemm_a16(
    const _Float16* __restrict__ A, int lda,
    const float* __restrict__ B, int ldb,
    const float* __restrict__ bias,
    void* __restrict__ Cv, int ldc, int K, int Mvalid, int ntn, int c16)
{
    __shared__ _Float16 As[8192];
    __shared__ _Float16 Bs[8192];

    const int nwg = gridDim.x;
    const int id = blockIdx.x;
    const int q = nwg >> 3, r = nwg & 7;
    const int xcd = id & 7, ix = id >> 3;
    const int wg = (xcd < r) ? (xcd * (q + 1) + ix) : (r * (q + 1) + (xcd - r) * q + ix);
    const int per = ntn << 3;
    const int g = wg / per, rem = wg % per;
    const int mt = g * 8 + (rem & 7), nt = rem >> 3;

    const int t = threadIdx.x, lane = t & 63, wid = t >> 6;
    const int wr = wid >> 1, wc = wid & 1;

    const int arow_s = t >> 3, ac8 = t & 7;
    const int brow_s = t >> 4, bc4 = t & 15;
    const _Float16* Ap = A + (size_t)(mt * 128 + arow_s) * lda + ac8 * 8;
    const float*    Bp = B + (size_t)(nt * 128 + brow_s) * ldb + bc4 * 4;
    const int awx = (ac8 * 8) ^ ((arow_s & 7) << 3);
    const int bwx = (bc4 * 4) ^ ((brow_s & 7) << 3);

    const int kts = K >> 6;
    f32x4 acc[4][4] = {};
    f16x8 ra[4]; float4 rb[8];
    #pragma unroll
    for (int i = 0; i < 4; ++i) ra[i] = *(const f16x8*)(Ap + (size_t)i * 32 * lda);
    #pragma unroll
    for (int i = 0; i < 8; ++i) rb[i] = *(const float4*)(Bp + (size_t)i * 16 * ldb);

    const int abase = (wr * 64 + (lane & 15)) * 64 + (lane >> 4) * 8;
    const int bbase = (wc * 64 + (lane & 15)) * 64 + (lane >> 4) * 8;
    const int sxor = (lane & 7) << 3;

    for (int kt = 0; kt < kts; ++kt) {
        f16x4 cb[8];
        #pragma unroll
        for (int i = 0; i < 8; ++i)
            cb[i] = (f16x4){(_Float16)rb[i].x, (_Float16)rb[i].y, (_Float16)rb[i].z, (_Float16)rb[i].w};
        __syncthreads();
        #pragma unroll
        for (int i = 0; i < 4; ++i)
            *(f16x8*)&As[(arow_s + i * 32) * 64 + awx] = ra[i];
        #pragma unroll
        for (int i = 0; i < 8; ++i)
            *(f16x4*)&Bs[(brow_s + i * 16) * 64 + bwx] = cb[i];
        __syncthreads();
        if (kt + 1 < kts) {
            #pragma unroll
            for (int i = 0; i < 4; ++i) ra[i] = *(const f16x8*)(Ap + (size_t)i * 32 * lda + (kt + 1) * 64);
            #pragma unroll
            for (int i = 0; i < 8; ++i) rb[i] = *(const float4*)(Bp + (size_t)i * 16 * ldb + (kt + 1) * 64);
        }
        #pragma unroll
        for (int kk = 0; kk < 2; ++kk) {
            f16x8 af[4], bfr[4];
            #pragma unroll
            for (int m = 0; m < 4; ++m) af[m]  = *(const f16x8*)&As[(abase + m * 16 * 64 + kk * 32) ^ sxor];
            #pragma unroll
            for (int n = 0; n < 4; ++n) bfr[n] = *(const f16x8*)&Bs[(bbase + n * 16 * 64 + kk * 32) ^ sxor];
            #pragma unroll
            for (int m = 0; m < 4; ++m)
                #pragma unroll
                for (int n = 0; n < 4; ++n)
                    acc[m][n] = __builtin_amdgcn_mfma_f32_16x16x32_f16(af[m], bfr[n], acc[m][n], 0, 0, 0);
        }
    }

    const int ccol = nt * 128 + wc * 64 + (lane & 15);
    const int crow0 = mt * 128 + wr * 64 + ((lane >> 4) << 2);
    float bv[4];
    #pragma unroll
    for (int n = 0; n < 4; ++n) bv[n] = bias[ccol + n * 16];
    #pragma unroll
    for (int m = 0; m < 4; ++m) {
        #pragma unroll
        for (int rI = 0; rI < 4; ++rI) {
            const int row = crow0 + m * 16 + rI;
            if (row < Mvalid) {
                if (c16) {
                    _Float16* C = (_Float16*)Cv;
                    #pragma unroll
                    for (int n = 0; n < 4; ++n)
                        C[(size_t)row * ldc + ccol + n * 16] = (_Float16)(acc[m][n][rI] + bv[n]);
                } else {
                    float* C = (float*)Cv;
                    #pragma unroll
                    for (int n = 0; n < 4; ++n)
                        C[(size_t)row * ldc + ccol + n * 16] = acc[m][n][rI] + bv[n];
                }
            }
        }
    }
}

// ================= launch =================
extern "C" void kernel_launch(void* const* d_in, const int* in_sizes, int n_in,
                              void* d_out, int out_size, void* d_ws, size_t ws_size,
                              hipStream_t stream) {
    const int*   src     = (const int*)d_in[0];
    const int*   trg     = (const int*)d_in[1];
    const float* enc_emb = (const float*)d_in[2];
    const float* Wf_ih   = (const float*)d_in[3];
    const float* Wf_hh   = (const float*)d_in[4];
    const float* bf      = (const float*)d_in[5];
    const float* Wb_ih   = (const float*)d_in[6];
    const float* Wb_hh   = (const float*)d_in[7];
    const float* bb      = (const float*)d_in[8];
    const float* Wa      = (const float*)d_in[9];
    const float* ba      = (const float*)d_in[10];
    const float* vvec    = (const float*)d_in[11];
    const float* dec_emb = (const float*)d_in[12];
    const float* Wd_ih   = (const float*)d_in[13];
    const float* Wd_hh   = (const float*)d_in[14];
    const float* bd      = (const float*)d_in[15];
    const float* Wo      = (const float*)d_in[16];
    const float* bo      = (const float*)d_in[17];
    float* out = (float*)d_out;

    char* w = (char*)d_ws;
    _Float16* Wenc16     = (_Float16*)(w);               // 8,388,608 B
    _Float16* Wd16       = (_Float16*)(w + 8388608);     // 20,971,520 B
    _Float16* Wa16       = (_Float16*)(w + 29360128);    // 524,288 B
    _Float16* emb_src16  = (_Float16*)(w + 29884416);    // 8,388,608 B
    _Float16* enc_out16  = (_Float16*)(w + 38273024);    // 16,777,216 B
    _Float16* predA      = (_Float16*)(w + 55050240);    // 21,299,200 B (4160 x 2560)
    _Float16* h16_enc    = (_Float16*)(w + 76349440);    // 262,144 B
    float*    c_enc      = (float*)   (w + 76611584);    // 524,288 B
    float*    c_dec      = (float*)   (w + 77135872);    // 524,288 B
    float*    hatt       = (float*)   (w + 77660160);    // 65,536 B
    _Float16* enc_part16 = (_Float16*)(w + 77725696);    // 4,194,304 B
    int*      bar_ws     = (int*)     (w + 81920000);    // 2,621,440 B: 640 slots x 4KB
    const size_t need_bytes = 84541440;
    if (ws_size < need_bytes) return;

    init_convert<<<93888, 256, 0, stream>>>(
        src, trg, enc_emb, dec_emb, Wf_ih, Wf_hh, Wb_ih, Wb_hh, Wa, Wd_ih, Wd_hh,
        out, Wenc16, Wd16, Wa16, emb_src16, predA, c_enc, h16_enc, bar_ws);

    // ---- encoder (cooperative, 4 independent 64-block groups; fallback per-step) ----
    {
        const _Float16* a0 = Wenc16; const _Float16* a1 = emb_src16;
        _Float16* a2 = h16_enc; float* a3 = c_enc;
        const float* a4 = bf; const float* a5 = bb;
        _Float16* a6 = enc_out16; int* a7 = bar_ws;
        void* args[] = { &a0, &a1, &a2, &a3, &a4, &a5, &a6, &a7 };
        hipError_t e = hipLaunchCooperativeKernel((const void*)enc_coop, dim3(256), dim3(256), args, 0, stream);
        if (e != hipSuccess) {
            for (int s = 0; s < SLEN; ++s)
                enc_step_mfma<<<256, 64, 0, stream>>>(Wenc16, emb_src16, h16_enc, c_enc, bf, bb, enc_out16, s);
        }
    }

    // enc_part16 = enc_out16 @ Wa[:,1024:]^T + ba
    gemm_a16<<<128, 256, 0, stream>>>(enc_out16, 1024, Wa + 1024, 2048, ba,
                                      enc_part16, 256, 1024, 8192, 2, 1);

    // ---- decoder (cooperative, 64 attn + 256 gate blocks; fallback per-step) ----
    {
        const _Float16* a0 = Wd16; const _Float16* a1 = Wa16;
        const float* a2 = bd; const float* a3 = vvec;
        const int* a4 = src; const _Float16* a5 = enc_part16;
        const _Float16* a6 = enc_out16; const float* a7 = c_enc;
        _Float16* a8 = predA; int* a9 = bar_ws;
        void* args[] = { &a0, &a1, &a2, &a3, &a4, &a5, &a6, &a7, &a8, &a9 };
        hipError_t e = hipLaunchCooperativeKernel((const void*)dec_coop, dim3(320), dim3(256), args, 0, stream);
        if (e != hipSuccess) {
            dec_init<<<512, 256, 0, stream>>>(enc_out16, c_enc, predA, c_dec);
            for (int t = 0; t < TSTEPS; ++t) {
                hatt_mfma<<<16, 64, 0, stream>>>(predA, Wa16, hatt, t);
                attn_step<<<64, 256, 0, stream>>>(src, hatt, vvec, enc_part16, enc_out16, predA, t);
                dec_gates<<<256, 64, 0, stream>>>(Wd16, bd, c_dec, predA, t);
            }
        }
    }

    // out[64.. , :] = predA[64..] @ Wo^T + bo
    gemm_a16<<<8000, 256, 0, stream>>>(predA + (size_t)64 * 2560, 2560, Wo, 2560, bo,
                                       out + (size_t)64 * VOC, VOC, 2560, 4032, 250, 0);
}

// Round 11
// 5116.154 us; speedup vs baseline: 1.3423x; 1.2173x over previous
//
#include <hip/hip_runtime.h>

#define SLEN  128
#define BATCH 64
#define EMB   512
#define HID   512
#define DDEC  1024
#define ATT   256
#define VOC   32000
#define TSTEPS 63
#define SLOT  1024   // ints per 4KB slot

typedef _Float16 f16x4 __attribute__((ext_vector_type(4)));
typedef _Float16 f16x8 __attribute__((ext_vector_type(8)));
typedef float    f32x4 __attribute__((ext_vector_type(4)));

union HQ  { unsigned long long q[2]; f16x8 v; };
union HP  { _Float16 h[2]; unsigned u; };
union HP4 { _Float16 h[4]; f16x4 v4; unsigned long long u; };

__device__ __forceinline__ float sigmoidf_(float x) { return 1.0f / (1.0f + __expf(-x)); }
__device__ __forceinline__ float tanhf_(float x)    { return 1.0f - 2.0f / (__expf(2.0f * x) + 1.0f); }

__device__ __forceinline__ void st_u32(void* p, unsigned v) {
    __hip_atomic_store((unsigned*)p, v, __ATOMIC_RELAXED, __HIP_MEMORY_SCOPE_AGENT);
}
__device__ __forceinline__ void st_u64(void* p, unsigned long long v) {
    __hip_atomic_store((unsigned long long*)p, v, __ATOMIC_RELAXED, __HIP_MEMORY_SCOPE_AGENT);
}
__device__ __forceinline__ unsigned long long ld_u64(const void* p) {
    return __hip_atomic_load((const unsigned long long*)p, __ATOMIC_RELAXED, __HIP_MEMORY_SCOPE_AGENT);
}
__device__ __forceinline__ void st_i32(int* p, int v) {
    __hip_atomic_store(p, v, __ATOMIC_RELAXED, __HIP_MEMORY_SCOPE_AGENT);
}
__device__ __forceinline__ int ld_i32(const int* p) {
    return __hip_atomic_load(p, __ATOMIC_RELAXED, __HIP_MEMORY_SCOPE_AGENT);
}

// ---- detector-free barrier: arrival = 1 relaxed store; wave-0 polls all flags.
__device__ __forceinline__ void bar_arrive(int* flags, int myid, int epoch) {
    __syncthreads();                       // drains this block's data stores (vmcnt 0)
    if (threadIdx.x == 0) st_i32(flags + myid * SLOT, epoch);
}
__device__ __forceinline__ void bar_wait(int* flags, int nf, int epoch) {
    if ((int)threadIdx.x < 64) {
        bool done = false;
        while (!done) {
            bool ok = true;
            for (int i = threadIdx.x; i < nf; i += 64)
                ok = ok && (ld_i32(flags + i * SLOT) >= epoch);
            done = __all(ok);
            if (!done) __builtin_amdgcn_s_sleep(1);
        }
    }
    __syncthreads();
}

// ================= init =================
__global__ __launch_bounds__(256) void init_convert(
    const int* __restrict__ src, const int* __restrict__ trg,
    const float* __restrict__ enc_emb, const float* __restrict__ dec_emb,
    const float* __restrict__ Wf_ih, const float* __restrict__ Wf_hh,
    const float* __restrict__ Wb_ih, const float* __restrict__ Wb_hh,
    const float* __restrict__ Wa, const float* __restrict__ Wd_ih, const float* __restrict__ Wd_hh,
    float* __restrict__ out0,
    _Float16* __restrict__ Wenc16, _Float16* __restrict__ Wd16, _Float16* __restrict__ Wa16,
    _Float16* __restrict__ emb_src16, _Float16* __restrict__ predA,
    float* __restrict__ c_enc, _Float16* __restrict__ h16_enc, int* __restrict__ bar_ws)
{
    long idx = (long)blockIdx.x * 256 + threadIdx.x;
    if (idx < 2048000L) { out0[idx] = 0.f; return; }
    idx -= 2048000L;
    if (idx < 4194304L) {   // Wenc16 [dir][2048][1024]
        int dir = (int)(idx >> 21);
        int rem = (int)(idx & ((1 << 21) - 1));
        int rr = rem >> 10, c = rem & 1023;
        int d = rr >> 2, qg = rr & 3;
        const float* Wih = dir ? Wb_ih : Wf_ih;
        const float* Whh = dir ? Wb_hh : Wf_hh;
        float v = (c < 512) ? Wih[(long)(qg * 512 + d) * 512 + c]
                            : Whh[(long)(qg * 512 + d) * 512 + (c - 512)];
        Wenc16[idx] = (_Float16)v; return;
    }
    idx -= 4194304L;
    if (idx < 10485760L) {  // Wd16 [4096][2560]
        int rr = (int)(idx / 2560), c = (int)(idx % 2560);
        int d = rr >> 2, qg = rr & 3;
        float v = (c < 1536) ? Wd_ih[(long)(qg * 1024 + d) * 1536 + c]
                             : Wd_hh[(long)(qg * 1024 + d) * 1024 + (c - 1536)];
        Wd16[idx] = (_Float16)v; return;
    }
    idx -= 10485760L;
    if (idx < 262144L) {    // Wa16 [256][1024]
        int rr = (int)(idx >> 10), c = (int)(idx & 1023);
        Wa16[idx] = (_Float16)Wa[(long)rr * 2048 + c]; return;
    }
    idx -= 262144L;
    if (idx < 4194304L) {   // emb_src16
        int sb = (int)(idx >> 9), e = (int)(idx & 511);
        int tok = src[sb];
        emb_src16[idx] = (_Float16)enc_emb[(long)tok * 512 + e]; return;
    }
    idx -= 4194304L;
    if (idx < 2064384L) {   // predA emb cols
        int rI = (int)(idx >> 9), e = (int)(idx & 511);
        int tok = trg[rI];
        predA[(long)(64 + rI) * 2560 + 2048 + e] = (_Float16)dec_emb[(long)tok * 512 + e]; return;
    }
    idx -= 2064384L;
    if (idx < 65536L) { c_enc[idx] = 0.f; return; }
    idx -= 65536L;
    if (idx < 65536L) { h16_enc[idx] = (_Float16)0.f; return; }
    idx -= 65536L;
    if (idx < 655360L) { bar_ws[idx] = 0; }   // 640 slots x 1024 ints
}

// ================= cooperative encoder: 4 groups (dir x batch-half) x 64 blocks x 256 thr =================
__global__ __launch_bounds__(256, 1) void enc_coop(
    const _Float16* __restrict__ Wenc16, const _Float16* __restrict__ emb_src16,
    _Float16* __restrict__ h16_enc, float* __restrict__ c_enc,
    const float* __restrict__ bf, const float* __restrict__ bb,
    _Float16* __restrict__ enc_out16, int* __restrict__ bar_ws)
{
    __shared__ _Float16 Wl[32768];       // 64KB [kc32][gt2][512]
    __shared__ float gbuf[32][34];

    const int t = threadIdx.x, lane = t & 63, wv = t >> 6;
    const int blk = blockIdx.x;
    const int g = blk >> 6, wb = blk & 63;
    const int dir = g >> 1, bh = g & 1;
    const int r16 = lane & 15, kg = lane >> 4;
    int* eflags = bar_ws + (384 + g * 64) * SLOT;

    #pragma unroll
    for (int i = 0; i < 16; ++i) {
        int h0 = (i * 256 + t) * 8;
        int kc = h0 >> 10;
        int rem = h0 & 1023;
        int gt2 = rem >> 9, l = (rem >> 3) & 63;
        f16x8 v = *(const f16x8*)(Wenc16 +
            ((size_t)(dir * 2048 + wb * 32 + gt2 * 16 + (l & 15))) * 1024 + (l >> 4) * 8 + kc * 32);
        *(f16x8*)&Wl[h0] = v;
    }

    const float* bias = dir ? bb : bf;
    const int pb = t & 31, dp = t >> 5;
    const int dl0 = dp * 2;
    float bias2[2][4], creg2[2] = {0.f, 0.f};
    if (t < 128) {
        #pragma unroll
        for (int j = 0; j < 2; ++j)
            #pragma unroll
            for (int q = 0; q < 4; ++q)
                bias2[j][q] = bias[q * 512 + wb * 8 + dl0 + j];
    }
    __syncthreads();

    for (int s = 0; s < SLEN; ++s) {
        const int par = s & 1;
        const int s_eff = dir ? (127 - s) : s;
        const int gt = wv & 1, mb = wv >> 1;
        const int arow = bh * 32 + mb * 16 + r16;
        const _Float16* Ax = emb_src16 + ((size_t)(s_eff * 64 + arow)) * 512 + kg * 8;
        const unsigned long long* Hq =
            (const unsigned long long*)(h16_enc + ((size_t)((par * 2 + dir) * 64 + arow)) * 512);
        f32x4 acc = {};
        #pragma unroll 4
        for (int kc = 0; kc < 16; ++kc) {
            f16x8 bw = *(const f16x8*)&Wl[kc * 1024 + gt * 512 + lane * 8];
            f16x8 a  = *(const f16x8*)(Ax + kc * 32);
            acc = __builtin_amdgcn_mfma_f32_16x16x32_f16(a, bw, acc, 0, 0, 0);
        }
        #pragma unroll 4
        for (int kc = 0; kc < 16; ++kc) {
            f16x8 bw = *(const f16x8*)&Wl[(16 + kc) * 1024 + gt * 512 + lane * 8];
            HQ hq;
            hq.q[0] = ld_u64(Hq + kc * 8 + kg * 2);
            hq.q[1] = ld_u64(Hq + kc * 8 + kg * 2 + 1);
            acc = __builtin_amdgcn_mfma_f32_16x16x32_f16(hq.v, bw, acc, 0, 0, 0);
        }
        #pragma unroll
        for (int rI = 0; rI < 4; ++rI)
            gbuf[gt * 16 + (lane & 15)][mb * 16 + kg * 4 + rI] = acc[rI];
        __syncthreads();
        if (t < 128) {
            HP hp;
            #pragma unroll
            for (int j = 0; j < 2; ++j) {
                const int dl = dl0 + j;
                float g0 = gbuf[dl * 4 + 0][pb] + bias2[j][0];
                float g1 = gbuf[dl * 4 + 1][pb] + bias2[j][1];
                float g2 = gbuf[dl * 4 + 2][pb] + bias2[j][2];
                float g3 = gbuf[dl * 4 + 3][pb] + bias2[j][3];
                float c2 = sigmoidf_(g1) * creg2[j] + sigmoidf_(g0) * tanhf_(g2);
                float h2 = sigmoidf_(g3) * tanhf_(c2);
                creg2[j] = c2;
                hp.h[j] = (_Float16)h2;
            }
            const int bglob = bh * 32 + pb;
            const int d0 = wb * 8 + dl0;
            st_u32((void*)(h16_enc + ((size_t)((par ^ 1) * 2 + dir) * 64 + bglob) * 512 + d0), hp.u);
            *(unsigned*)(enc_out16 + ((size_t)s_eff * 64 + bglob) * 1024 + dir * 512 + d0) = hp.u;
        }
        bar_arrive(eflags, wb, s + 1);
        bar_wait(eflags, 64, s + 1);
    }
    if (t < 128) {
        const int bglob = bh * 32 + pb;
        const int d0 = wb * 8 + dl0;
        c_enc[((size_t)dir * 64 + bglob) * 512 + d0] = creg2[0];
        c_enc[((size_t)dir * 64 + bglob) * 512 + d0 + 1] = creg2[1];
    }
}

// ================= cooperative decoder: 256 blocks x 256 thr =================
// Every block: 16 Wd rows in LDS (80KB), gates for d in [blk*4, blk*4+4), all 64 batch.
// Blocks 0-63 additionally run attention for batch = blk.
// Gates overlap emb+h K-segments with attention; only ctx segment waits on cf barrier.
__global__ __launch_bounds__(256, 1) void dec_coop(
    const _Float16* __restrict__ Wd16, const _Float16* __restrict__ Wa16,
    const float* __restrict__ bd, const float* __restrict__ vvec,
    const int* __restrict__ src, const _Float16* __restrict__ enc_part16,
    const _Float16* __restrict__ enc_out16, const float* __restrict__ c_enc,
    _Float16* __restrict__ predA, int* __restrict__ bar_ws)
{
    __shared__ _Float16 Wl[40960];       // 80KB: 80 chunks x 512 halves, fragment-linear
    __shared__ float gbuf[16][68];
    __shared__ float ha[256], sv[256], sc[128], esum[256], red[4];

    const int t = threadIdx.x, lane = t & 63, wv = t >> 6;
    const int r16 = lane & 15, kg = lane >> 4;
    const int blk = blockIdx.x;
    const int gid = blk;                 // gate-row group (16 rows = 4 d)
    int* cf  = bar_ws;                   // 64 ctx flags
    int* hs  = bar_ws + 64 * SLOT;       // 256 h flags
    int* hf0 = bar_ws + 320 * SLOT;      // 64 h0 flags

    // stage Wd slice into LDS (once)
    #pragma unroll
    for (int i = 0; i < 20; ++i) {
        int h0 = (i * 256 + t) * 8;
        int kc = h0 >> 9, l = (h0 >> 3) & 63;
        f16x8 v = *(const f16x8*)(Wd16 + ((size_t)(gid * 16 + (l & 15))) * 2560 + (l >> 4) * 8 + kc * 32);
        *(f16x8*)&Wl[h0] = v;
    }

    // gate pointwise state (all blocks)
    const int pb = t & 63;
    const int dl0 = (t >> 6) * 2;        // only t<128 meaningful
    float bias2[2][4], creg2[2] = {0.f, 0.f};
    if (t < 128) {
        #pragma unroll
        for (int j = 0; j < 2; ++j) {
            const int dg = gid * 4 + dl0 + j;
            #pragma unroll
            for (int q = 0; q < 4; ++q) bias2[j][q] = bd[q * 1024 + dg];
            creg2[j] = (dg < 512) ? c_enc[(size_t)pb * 512 + dg]
                                  : c_enc[(size_t)(64 + pb) * 512 + (dg - 512)];
        }
    }

    if (blk < 64) {
        sv[t] = vvec[t];
        {   // h0 for batch blk -> predA row blk
            const int d0 = t * 4;
            const size_t rbase = (d0 < 512) ? (size_t)(127 * 64 + blk) * 1024
                                            : (size_t)(0 * 64 + blk) * 1024;
            HP4 o;
            o.h[0] = enc_out16[rbase + d0];
            o.h[1] = enc_out16[rbase + d0 + 1];
            o.h[2] = enc_out16[rbase + d0 + 2];
            o.h[3] = enc_out16[rbase + d0 + 3];
            st_u64((void*)(predA + (size_t)blk * 2560 + d0), o.u);
        }
        bar_arrive(hf0, blk, 1);
    } else {
        __syncthreads();   // match bar_arrive's syncthreads shape (not required, harmless)
    }

    for (int tt = 0; tt < TSTEPS; ++tt) {
        if (tt == 0) bar_wait(hf0, 64, 1); else bar_wait(hs, 256, tt);

        if (blk < 64) {
            const int wb = blk;
            // P1: hatt via 16-batch-group MFMA
            {
                const int base_m = wb & 48;
                const _Float16* Ahh = predA + ((size_t)(tt * 64 + base_m + r16)) * 2560 + kg * 8;
                f32x4 acc4[4] = {};
                #pragma unroll 4
                for (int kc = 0; kc < 32; ++kc) {
                    f16x8 a = *(const f16x8*)(Ahh + kc * 32);
                    #pragma unroll
                    for (int jj = 0; jj < 4; ++jj) {
                        f16x8 bw = *(const f16x8*)(Wa16 +
                            ((size_t)((wv * 4 + jj) * 16 + r16)) * 1024 + kg * 8 + kc * 32);
                        acc4[jj] = __builtin_amdgcn_mfma_f32_16x16x32_f16(a, bw, acc4[jj], 0, 0, 0);
                    }
                }
                if (kg == ((wb & 15) >> 2)) {
                    #pragma unroll
                    for (int jj = 0; jj < 4; ++jj)
                        ha[(wv * 4 + jj) * 16 + r16] = acc4[jj][wb & 3];
                }
            }
            __syncthreads();
            // P2: energy (all 256 threads: s = t&127, j-half = t>>7)
            {
                const int s = t & 127, jh = t >> 7;
                const f16x8* ep = (const f16x8*)(enc_part16 + ((size_t)s * 64 + wb) * 256 + jh * 128);
                float acc = 0.f;
                #pragma unroll 2
                for (int j8 = 0; j8 < 16; ++j8) {
                    f16x8 e = ep[j8];
                    #pragma unroll
                    for (int u = 0; u < 8; ++u)
                        acc += tanhf_(ha[jh * 128 + j8 * 8 + u] + (float)e[u]) * sv[jh * 128 + j8 * 8 + u];
                }
                esum[t] = acc;
            }
            __syncthreads();
            if (t < 128) {
                float scv = esum[t] + esum[128 + t];
                scv = (src[t * 64 + wb] != 0) ? scv : -1e10f;
                sc[t] = scv;
                float v = scv;
                #pragma unroll
                for (int off = 32; off > 0; off >>= 1) v = fmaxf(v, __shfl_xor(v, off));
                if (lane == 0) red[t >> 6] = v;
            }
            __syncthreads();
            {
                const float mx = fmaxf(red[0], red[1]);
                if (t < 128) {
                    float e = __expf(sc[t] - mx);
                    sc[t] = e;
                    float v = e;
                    #pragma unroll
                    for (int off = 32; off > 0; off >>= 1) v += __shfl_xor(v, off);
                    if (lane == 0) red[2 + (t >> 6)] = v;
                }
            }
            __syncthreads();
            {
                const float inv = 1.0f / (red[2] + red[3]);
                float a0 = 0.f, a1 = 0.f, a2 = 0.f, a3 = 0.f;
                #pragma unroll 4
                for (int sI = 0; sI < 128; ++sI) {
                    float as = sc[sI] * inv;
                    f16x4 ev = *(const f16x4*)(enc_out16 + ((size_t)sI * 64 + wb) * 1024 + t * 4);
                    a0 += as * (float)ev[0]; a1 += as * (float)ev[1];
                    a2 += as * (float)ev[2]; a3 += as * (float)ev[3];
                }
                HP4 o;
                o.h[0] = (_Float16)a0; o.h[1] = (_Float16)a1;
                o.h[2] = (_Float16)a2; o.h[3] = (_Float16)a3;
                st_u64((void*)(predA + ((size_t)(64 + tt * 64 + wb)) * 2560 + 1024 + t * 4), o.u);
            }
            bar_arrive(cf, wb, tt + 1);
        }

        // ---- gates: 16 rows x 64 batch; B from LDS; A direct loads
        {
            const int mb = wv;   // 4 waves = 4 batch tiles of 16
            const _Float16* Ae = predA + ((size_t)(64 + tt * 64 + mb * 16 + r16)) * 2560 + kg * 8;
            const _Float16* Ah = predA + ((size_t)(tt * 64 + mb * 16 + r16)) * 2560 + kg * 8;
            f32x4 acc = {};
            // partial: emb (chunks 0..15) + h (chunks 48..79) — no ctx dependency
            #pragma unroll 4
            for (int kc = 0; kc < 16; ++kc) {
                f16x8 bw = *(const f16x8*)&Wl[kc * 512 + lane * 8];
                f16x8 a  = *(const f16x8*)(Ae + 2048 + kc * 32);
                acc = __builtin_amdgcn_mfma_f32_16x16x32_f16(a, bw, acc, 0, 0, 0);
            }
            #pragma unroll 4
            for (int kc = 0; kc < 32; ++kc) {
                f16x8 bw = *(const f16x8*)&Wl[(48 + kc) * 512 + lane * 8];
                f16x8 a  = *(const f16x8*)(Ah + kc * 32);
                acc = __builtin_amdgcn_mfma_f32_16x16x32_f16(a, bw, acc, 0, 0, 0);
            }
            bar_wait(cf, 64, tt + 1);
            // ctx part (chunks 16..47)
            #pragma unroll 4
            for (int kc = 0; kc < 32; ++kc) {
                f16x8 bw = *(const f16x8*)&Wl[(16 + kc) * 512 + lane * 8];
                f16x8 a  = *(const f16x8*)(Ae + 1024 + kc * 32);
                acc = __builtin_amdgcn_mfma_f32_16x16x32_f16(a, bw, acc, 0, 0, 0);
            }
            // C/D: col=lane&15 -> gate row (N), row=kg*4+rI -> batch (M)
            #pragma unroll
            for (int rI = 0; rI < 4; ++rI)
                gbuf[lane & 15][mb * 16 + kg * 4 + rI] = acc[rI];
        }
        __syncthreads();
        if (t < 128) {
            HP hp;
            #pragma unroll
            for (int j = 0; j < 2; ++j) {
                const int dl = dl0 + j;
                float g0 = gbuf[dl * 4 + 0][pb] + bias2[j][0];
                float g1 = gbuf[dl * 4 + 1][pb] + bias2[j][1];
                float g2 = gbuf[dl * 4 + 2][pb] + bias2[j][2];
                float g3 = gbuf[dl * 4 + 3][pb] + bias2[j][3];
                float c2 = sigmoidf_(g1) * creg2[j] + sigmoidf_(g0) * tanhf_(g2);
                float h2 = sigmoidf_(g3) * tanhf_(c2);
                creg2[j] = c2;
                hp.h[j] = (_Float16)h2;
            }
            st_u32((void*)(predA + ((size_t)(64 + tt * 64 + pb)) * 2560 + gid * 4 + dl0), hp.u);
        }
        bar_arrive(hs, gid, tt + 1);
    }
}

// ================= fallback per-step kernels (validated) =================
__global__ __launch_bounds__(64) void enc_step_mfma(
    const _Float16* __restrict__ Wenc16, const _Float16* __restrict__ emb_src16,
    _Float16* __restrict__ h16_enc, float* __restrict__ c_enc,
    const float* __restrict__ bf, const float* __restrict__ bb,
    _Float16* __restrict__ enc_out16, int s)
{
    __shared__ float gbuf[16 * 66];
    const int lane = threadIdx.x;
    const int blk = blockIdx.x;
    const int dir = blk >> 7, tile = blk & 127;
    const int par = s & 1;
    const int s_eff = dir ? (SLEN - 1 - s) : s;
    const int r16 = lane & 15, kg = lane >> 4;

    const _Float16* Bw = Wenc16 + ((size_t)(dir * 2048 + tile * 16 + r16)) * 1024 + kg * 8;
    const _Float16* Ax = emb_src16 + ((size_t)(s_eff * 64 + r16)) * 512 + kg * 8;
    const _Float16* Ah = h16_enc + ((size_t)((par * 2 + dir) * 64 + r16)) * 512 + kg * 8;

    f32x4 acc[4] = {};
    #pragma unroll 4
    for (int kc = 0; kc < 16; ++kc) {
        f16x8 bfr = *(const f16x8*)(Bw + kc * 32);
        #pragma unroll
        for (int m = 0; m < 4; ++m) {
            f16x8 a = *(const f16x8*)(Ax + kc * 32 + (size_t)m * 16 * 512);
            acc[m] = __builtin_amdgcn_mfma_f32_16x16x32_f16(a, bfr, acc[m], 0, 0, 0);
        }
    }
    #pragma unroll 4
    for (int kc = 0; kc < 16; ++kc) {
        f16x8 bfr = *(const f16x8*)(Bw + 512 + kc * 32);
        #pragma unroll
        for (int m = 0; m < 4; ++m) {
            f16x8 a = *(const f16x8*)(Ah + kc * 32 + (size_t)m * 16 * 512);
            acc[m] = __builtin_amdgcn_mfma_f32_16x16x32_f16(a, bfr, acc[m], 0, 0, 0);
        }
    }
    #pragma unroll
    for (int m = 0; m < 4; ++m)
        #pragma unroll
        for (int rI = 0; rI < 4; ++rI)
            gbuf[r16 * 66 + m * 16 + kg * 4 + rI] = acc[m][rI];
    __syncthreads();

    const float* bias = dir ? bb : bf;
    const int b = lane;
    #pragma unroll
    for (int dl = 0; dl < 4; ++dl) {
        const int d = tile * 4 + dl;
        float g0 = gbuf[(dl * 4 + 0) * 66 + b] + bias[d];
        float g1 = gbuf[(dl * 4 + 1) * 66 + b] + bias[512 + d];
        float g2 = gbuf[(dl * 4 + 2) * 66 + b] + bias[1024 + d];
        float g3 = gbuf[(dl * 4 + 3) * 66 + b] + bias[1536 + d];
        const size_t cur = ((size_t)(par * 2 + dir) * 64 + b) * 512 + d;
        const size_t nxt = ((size_t)((par ^ 1) * 2 + dir) * 64 + b) * 512 + d;
        float c2 = sigmoidf_(g1) * c_enc[cur] + sigmoidf_(g0) * tanhf_(g2);
        float h2 = sigmoidf_(g3) * tanhf_(c2);
        c_enc[nxt] = c2;
        h16_enc[nxt] = (_Float16)h2;
        enc_out16[((size_t)s_eff * 64 + b) * 1024 + dir * 512 + d] = (_Float16)h2;
    }
}

__global__ __launch_bounds__(256) void dec_init(
    const _Float16* __restrict__ enc_out16, const float* __restrict__ c_enc,
    _Float16* __restrict__ predA, float* __restrict__ c_dec)
{
    int idx = blockIdx.x * 256 + threadIdx.x;
    int b = (idx >> 10) & 63, d = idx & 1023;
    if (idx < 65536) {
        _Float16 v = (d < 512) ? enc_out16[(size_t)(127 * 64 + b) * 1024 + d]
                               : enc_out16[(size_t)(0 * 64 + b) * 1024 + d];
        predA[(size_t)b * 2560 + d] = v;
    } else {
        float v = (d < 512) ? c_enc[((size_t)(0 * 2 + 0) * 64 + b) * 512 + d]
                            : c_enc[((size_t)(0 * 2 + 1) * 64 + b) * 512 + (d - 512)];
        c_dec[(size_t)b * 1024 + d] = v;
    }
}

__global__ __launch_bounds__(64) void hatt_mfma(
    const _Float16* __restrict__ predA, const _Float16* __restrict__ Wa16,
    float* __restrict__ hatt, int t)
{
    const int lane = threadIdx.x;
    const int tile = blockIdx.x;
    const int r16 = lane & 15, kg = lane >> 4;
    const _Float16* Ap = predA + ((size_t)(t * 64 + r16)) * 2560 + kg * 8;
    const _Float16* Bw = Wa16 + ((size_t)(tile * 16 + r16)) * 1024 + kg * 8;
    f32x4 acc[4] = {};
    #pragma unroll 4
    for (int kc = 0; kc < 32; ++kc) {
        f16x8 bfr = *(const f16x8*)(Bw + kc * 32);
        #pragma unroll
        for (int m = 0; m < 4; ++m) {
            f16x8 a = *(const f16x8*)(Ap + kc * 32 + (size_t)m * 16 * 2560);
            acc[m] = __builtin_amdgcn_mfma_f32_16x16x32_f16(a, bfr, acc[m], 0, 0, 0);
        }
    }
    #pragma unroll
    for (int m = 0; m < 4; ++m)
        #pragma unroll
        for (int rI = 0; rI < 4; ++rI)
            hatt[(size_t)(m * 16 + kg * 4 + rI) * 256 + tile * 16 + r16] = acc[m][rI];
}

__global__ __launch_bounds__(256) void attn_step(
    const int* __restrict__ src, const float* __restrict__ hatt, const float* __restrict__ vvec,
    const _Float16* __restrict__ enc_part16, const _Float16* __restrict__ enc_out16,
    _Float16* __restrict__ predA, int t)
{
    __shared__ float ha[256], sv[256], sc[128], red[128];
    const int b = blockIdx.x, tid = threadIdx.x;
    ha[tid] = hatt[b * 256 + tid];
    sv[tid] = vvec[tid];
    __syncthreads();
    if (tid < 128) {
        const f16x8* ep = (const f16x8*)(enc_part16 + ((size_t)tid * 64 + b) * 256);
        float acc = 0.f;
        #pragma unroll 4
        for (int j8 = 0; j8 < 32; ++j8) {
            f16x8 e = ep[j8];
            #pragma unroll
            for (int u = 0; u < 8; ++u)
                acc += tanhf_(ha[j8 * 8 + u] + (float)e[u]) * sv[j8 * 8 + u];
        }
        float scv = (src[tid * 64 + b] != 0) ? acc : -1e10f;
        sc[tid] = scv; red[tid] = scv;
    }
    __syncthreads();
    for (int off = 64; off > 0; off >>= 1) { if (tid < off) red[tid] = fmaxf(red[tid], red[tid + off]); __syncthreads(); }
    const float mx = red[0];
    __syncthreads();
    if (tid < 128) { float e = __expf(sc[tid] - mx); sc[tid] = e; red[tid] = e; }
    __syncthreads();
    for (int off = 64; off > 0; off >>= 1) { if (tid < off) red[tid] += red[tid + off]; __syncthreads(); }
    const float inv = 1.0f / red[0];
    __syncthreads();

    float a0 = 0.f, a1 = 0.f, a2 = 0.f, a3 = 0.f;
    for (int sI = 0; sI < 128; ++sI) {
        float as = sc[sI] * inv;
        f16x4 ev = *(const f16x4*)(enc_out16 + ((size_t)sI * 64 + b) * 1024 + tid * 4);
        a0 += as * (float)ev[0]; a1 += as * (float)ev[1];
        a2 += as * (float)ev[2]; a3 += as * (float)ev[3];
    }
    f16x4 o = { (_Float16)a0, (_Float16)a1, (_Float16)a2, (_Float16)a3 };
    *(f16x4*)(predA + ((size_t)(64 + t * 64 + b)) * 2560 + 1024 + tid * 4) = o;
}

__global__ __launch_bounds__(64) void dec_gates(
    const _Float16* __restrict__ Wd16, const float* __restrict__ bd,
    float* __restrict__ c_dec, _Float16* __restrict__ predA, int t)
{
    __shared__ float gbuf[16 * 66];
    const int lane = threadIdx.x;
    const int tile = blockIdx.x;
    const int par = t & 1;
    const int r16 = lane & 15, kg = lane >> 4;
    const _Float16* Bw = Wd16 + ((size_t)(tile * 16 + r16)) * 2560 + kg * 8;
    const _Float16* At = predA + ((size_t)(64 + t * 64 + r16)) * 2560 + kg * 8;
    const _Float16* Ah = predA + ((size_t)(t * 64 + r16)) * 2560 + kg * 8;
    f32x4 acc[4] = {};
    #pragma unroll 4
    for (int kc = 0; kc < 16; ++kc) {
        f16x8 bfr = *(const f16x8*)(Bw + kc * 32);
        #pragma unroll
        for (int m = 0; m < 4; ++m) {
            f16x8 a = *(const f16x8*)(At + 2048 + kc * 32 + (size_t)m * 16 * 2560);
            acc[m] = __builtin_amdgcn_mfma_f32_16x16x32_f16(a, bfr, acc[m], 0, 0, 0);
        }
    }
    #pragma unroll 4
    for (int kc = 0; kc < 32; ++kc) {
        f16x8 bfr = *(const f16x8*)(Bw + 512 + kc * 32);
        #pragma unroll
        for (int m = 0; m < 4; ++m) {
            f16x8 a = *(const f16x8*)(At + 1024 + kc * 32 + (size_t)m * 16 * 2560);
            acc[m] = __builtin_amdgcn_mfma_f32_16x16x32_f16(a, bfr, acc[m], 0, 0, 0);
        }
    }
    #pragma unroll 4
    for (int kc = 0; kc < 32; ++kc) {
        f16x8 bfr = *(const f16x8*)(Bw + 1536 + kc * 32);
        #pragma unroll
        for (int m = 0; m < 4; ++m) {
            f16x8 a = *(const f16x8*)(Ah + kc * 32 + (size_t)m * 16 * 2560);
            acc[m] = __builtin_amdgcn_mfma_f32_16x16x32_f16(a, bfr, acc[m], 0, 0, 0);
        }
    }
    #pragma unroll
    for (int m = 0; m < 4; ++m)
        #pragma unroll
        for (int rI = 0; rI < 4; ++rI)
            gbuf[r16 * 66 + m * 16 + kg * 4 + rI] = acc[m][rI];
    __syncthreads();

    const int b = lane;
    #pragma unroll
    for (int dl = 0; dl < 4; ++dl) {
        const int d = tile * 4 + dl;
        float g0 = gbuf[(dl * 4 + 0) * 66 + b] + bd[d];
        float g1 = gbuf[(dl * 4 + 1) * 66 + b] + bd[1024 + d];
        float g2 = gbuf[(dl * 4 + 2) * 66 + b] + bd[2048 + d];
        float g3 = gbuf[(dl * 4 + 3) * 66 + b] + bd[3072 + d];
        float c2 = sigmoidf_(g1) * c_dec[(size_t)(par * 64 + b) * 1024 + d] + sigmoidf_(g0) * tanhf_(g2);
        float h2 = sigmoidf_(g3) * tanhf_(c2);
        c_dec[(size_t)((par ^ 1) * 64 + b) * 1024 + d] = c2;
        predA[((size_t)(64 + t * 64 + b)) * 2560 + d] = (_Float16)h2;
    }
}

// ================= generic fp16-A MFMA GEMM =================
__global__ __launch_bounds__(256, 2) void gemm_a16(
    const _Float16* __restrict__ A, int lda,
    const float* __restrict__ B, int ldb,
    const float* __restrict__ bias,
    void* __restrict__ Cv, int ldc, int K, int Mvalid, int ntn, int c16)
{
    __shared__ _Float16 As[8192];
    __shared__ _Float16 Bs[8192];

    const int nwg = gridDim.x;
    const int id = blockIdx.x;
    const int q = nwg >> 3, r = nwg & 7;
    const int xcd = id & 7, ix = id >> 3;
    const int wg = (xcd < r) ? (xcd * (q + 1) + ix) : (r * (q + 1) + (xcd - r) * q + ix);
    const int per = ntn << 3;
    const int g = wg / per, rem = wg % per;
    const int mt = g * 8 + (rem & 7), nt = rem >> 3;

    const int t = threadIdx.x, lane = t & 63, wid = t >> 6;
    const int wr = wid >> 1, wc = wid & 1;

    const int arow_s = t >> 3, ac8 = t & 7;
    const int brow_s = t >> 4, bc4 = t & 15;
    const _Float16* Ap = A + (size_t)(mt * 128 + arow_s) * lda + ac8 * 8;
    const float*    Bp = B + (size_t)(nt * 128 + brow_s) * ldb + bc4 * 4;
    const int awx = (ac8 * 8) ^ ((arow_s & 7) << 3);
    const int bwx = (bc4 * 4) ^ ((brow_s & 7) << 3);

    const int kts = K >> 6;
    f32x4 acc[4][4] = {};
    f16x8 ra[4]; float4 rb[8];
    #pragma unroll
    for (int i = 0; i < 4; ++i) ra[i] = *(const f16x8*)(Ap + (size_t)i * 32 * lda);
    #pragma unroll
    for (int i = 0; i < 8; ++i) rb[i] = *(const float4*)(Bp + (size_t)i * 16 * ldb);

    const int abase = (wr * 64 + (lane & 15)) * 64 + (lane >> 4) * 8;
    const int bbase = (wc * 64 + (lane & 15)) * 64 + (lane >> 4) * 8;
    const int sxor = (lane & 7) << 3;

    for (int kt = 0; kt < kts; ++kt) {
        f16x4 cb[8];
        #pragma unroll
        for (int i = 0; i < 8; ++i)
            cb[i] = (f16x4){(_Float16)rb[i].x, (_Float16)rb[i].y, (_Float16)rb[i].z, (_Float16)rb[i].w};
        __syncthreads();
        #pragma unroll
        for (int i = 0; i < 4; ++i)
            *(f16x8*)&As[(arow_s + i * 32) * 64 + awx] = ra[i];
        #pragma unroll
        for (int i = 0; i < 8; ++i)
            *(f16x4*)&Bs[(brow_s + i * 16) * 64 + bwx] = cb[i];
        __syncthreads();
        if (kt + 1 < kts) {
            #pragma unroll
            for (int i = 0; i < 4; ++i) ra[i] = *(const f16x8*)(Ap + (size_t)i * 32 * lda + (kt + 1) * 64);
            #pragma unroll
            for (int i = 0; i < 8; ++i) rb[i] = *(const float4*)(Bp + (size_t)i * 16 * ldb + (kt + 1) * 64);
        }
        #pragma unroll
        for (int kk = 0; kk < 2; ++kk) {
            f16x8 af[4], bfr[4];
            #pragma unroll
            for (int m = 0; m < 4; ++m) af[m]  = *(const f16x8*)&As[(abase + m * 16 * 64 + kk * 32) ^ sxor];
            #pragma unroll
            for (int n = 0; n < 4; ++n) bfr[n] = *(const f16x8*)&Bs[(bbase + n * 16 * 64 + kk * 32) ^ sxor];
            #pragma unroll
            for (int m = 0; m < 4; ++m)
                #pragma unroll
                for (int n = 0; n < 4; ++n)
                    acc[m][n] = __builtin_amdgcn_mfma_f32_16x16x32_f16(af[m], bfr[n], acc[m][n], 0, 0, 0);
        }
    }

    const int ccol = nt * 128 + wc * 64 + (lane & 15);
    const int crow0 = mt * 128 + wr * 64 + ((lane >> 4) << 2);
    float bv[4];
    #pragma unroll
    for (int n = 0; n < 4; ++n) bv[n] = bias[ccol + n * 16];
    #pragma unroll
    for (int m = 0; m < 4; ++m) {
        #pragma unroll
        for (int rI = 0; rI < 4; ++rI) {
            const int row = crow0 + m * 16 + rI;
            if (row < Mvalid) {
                if (c16) {
                    _Float16* C = (_Float16*)Cv;
                    #pragma unroll
                    for (int n = 0; n < 4; ++n)
                        C[(size_t)row * ldc + ccol + n * 16] = (_Float16)(acc[m][n][rI] + bv[n]);
                } else {
                    float* C = (float*)Cv;
                    #pragma unroll
                    for (int n = 0; n < 4; ++n)
                        C[(size_t)row * ldc + ccol + n * 16] = acc[m][n][rI] + bv[n];
                }
            }
        }
    }
}

// ================= launch =================
extern "C" void kernel_launch(void* const* d_in, const int* in_sizes, int n_in,
                              void* d_out, int out_size, void* d_ws, size_t ws_size,
                              hipStream_t stream) {
    const int*   src     = (const int*)d_in[0];
    const int*   trg     = (const int*)d_in[1];
    const float* enc_emb = (const float*)d_in[2];
    const float* Wf_ih   = (const float*)d_in[3];
    const float* Wf_hh   = (const float*)d_in[4];
    const float* bf      = (const float*)d_in[5];
    const float* Wb_ih   = (const float*)d_in[6];
    const float* Wb_hh   = (const float*)d_in[7];
    const float* bb      = (const float*)d_in[8];
    const float* Wa      = (const float*)d_in[9];
    const float* ba      = (const float*)d_in[10];
    const float* vvec    = (const float*)d_in[11];
    const float* dec_emb = (const float*)d_in[12];
    const float* Wd_ih   = (const float*)d_in[13];
    const float* Wd_hh   = (const float*)d_in[14];
    const float* bd      = (const float*)d_in[15];
    const float* Wo      = (const float*)d_in[16];
    const float* bo      = (const float*)d_in[17];
    float* out = (float*)d_out;

    char* w = (char*)d_ws;
    _Float16* Wenc16     = (_Float16*)(w);               // 8,388,608 B
    _Float16* Wd16       = (_Float16*)(w + 8388608);     // 20,971,520 B
    _Float16* Wa16       = (_Float16*)(w + 29360128);    // 524,288 B
    _Float16* emb_src16  = (_Float16*)(w + 29884416);    // 8,388,608 B
    _Float16* enc_out16  = (_Float16*)(w + 38273024);    // 16,777,216 B
    _Float16* predA      = (_Float16*)(w + 55050240);    // 21,299,200 B (4160 x 2560)
    _Float16* h16_enc    = (_Float16*)(w + 76349440);    // 262,144 B
    float*    c_enc      = (float*)   (w + 76611584);    // 524,288 B
    float*    c_dec      = (float*)   (w + 77135872);    // 524,288 B
    float*    hatt       = (float*)   (w + 77660160);    // 65,536 B
    _Float16* enc_part16 = (_Float16*)(w + 77725696);    // 4,194,304 B
    int*      bar_ws     = (int*)     (w + 81920000);    // 2,621,440 B: 640 slots x 4KB
    const size_t need_bytes = 84541440;
    if (ws_size < need_bytes) return;

    init_convert<<<93888, 256, 0, stream>>>(
        src, trg, enc_emb, dec_emb, Wf_ih, Wf_hh, Wb_ih, Wb_hh, Wa, Wd_ih, Wd_hh,
        out, Wenc16, Wd16, Wa16, emb_src16, predA, c_enc, h16_enc, bar_ws);

    // ---- encoder (cooperative, 4 independent 64-block groups; fallback per-step) ----
    {
        const _Float16* a0 = Wenc16; const _Float16* a1 = emb_src16;
        _Float16* a2 = h16_enc; float* a3 = c_enc;
        const float* a4 = bf; const float* a5 = bb;
        _Float16* a6 = enc_out16; int* a7 = bar_ws;
        void* args[] = { &a0, &a1, &a2, &a3, &a4, &a5, &a6, &a7 };
        hipError_t e = hipLaunchCooperativeKernel((const void*)enc_coop, dim3(256), dim3(256), args, 0, stream);
        if (e != hipSuccess) {
            for (int s = 0; s < SLEN; ++s)
                enc_step_mfma<<<256, 64, 0, stream>>>(Wenc16, emb_src16, h16_enc, c_enc, bf, bb, enc_out16, s);
        }
    }

    // enc_part16 = enc_out16 @ Wa[:,1024:]^T + ba
    gemm_a16<<<128, 256, 0, stream>>>(enc_out16, 1024, Wa + 1024, 2048, ba,
                                      enc_part16, 256, 1024, 8192, 2, 1);

    // ---- decoder (cooperative, 256 blocks, Wd in LDS, 64 blocks also attn; fallback per-step) ----
    {
        const _Float16* a0 = Wd16; const _Float16* a1 = Wa16;
        const float* a2 = bd; const float* a3 = vvec;
        const int* a4 = src; const _Float16* a5 = enc_part16;
        const _Float16* a6 = enc_out16; const float* a7 = c_enc;
        _Float16* a8 = predA; int* a9 = bar_ws;
        void* args[] = { &a0, &a1, &a2, &a3, &a4, &a5, &a6, &a7, &a8, &a9 };
        hipError_t e = hipLaunchCooperativeKernel((const void*)dec_coop, dim3(256), dim3(256), args, 0, stream);
        if (e != hipSuccess) {
            dec_init<<<512, 256, 0, stream>>>(enc_out16, c_enc, predA, c_dec);
            for (int t = 0; t < TSTEPS; ++t) {
                hatt_mfma<<<16, 64, 0, stream>>>(predA, Wa16, hatt, t);
                attn_step<<<64, 256, 0, stream>>>(src, hatt, vvec, enc_part16, enc_out16, predA, t);
                dec_gates<<<256, 64, 0, stream>>>(Wd16, bd, c_dec, predA, t);
            }
        }
    }

    // out[64.. , :] = predA[64..] @ Wo^T + bo
    gemm_a16<<<8000, 256, 0, stream>>>(predA + (size_t)64 * 2560, 2560, Wo, 2560, bo,
                                       out + (size_t)64 * VOC, VOC, 2560, 4032, 250, 0);
}